// Round 1
// baseline (1007.426 us; speedup 1.0000x reference)
//
#include <hip/hip_runtime.h>

// Problem constants: B=16, L=4096, H=8, E=64, K=64, F=2049 (rfft bins)
// Only bins m in [1,2048] matter (bin 0 excluded from top-k; out_ft uses slots 0..63).

#define NTHREADS 256

// ---------------- table kernel: trig[k] = (cos, sin)(2*pi*k/4096), f64-accurate ----------------
__global__ void k_tables(float2* __restrict__ trig) {
    int k = blockIdx.x * blockDim.x + threadIdx.x;
    if (k < 4096) {
        double th = (6.283185307179586476925286766559 * (double)k) / 4096.0;
        trig[k] = make_float2((float)cos(th), (float)sin(th));
    }
}

// ---------------- FFT + spectrum store + score accumulation ----------------
// grid: 1024 blocks = (b:16, h:8, eo:8). Each block: 4 complex FFTs covering e = 8*eo .. 8*eo+7
// (two real signals per complex FFT). X[m], m=1..2048 stored to Xout[sig*2048 + (m-1)].
__global__ __launch_bounds__(256) void k_fft(const float* __restrict__ q,
                                             const float2* __restrict__ trig,
                                             float2* __restrict__ Xout,
                                             unsigned long long* __restrict__ score) {
    __shared__ float2 z[4096];     // 32 KB
    __shared__ float2 tw[2048];    // 16 KB  e^{-2pi i k/4096}
    __shared__ float  eacc[2048];  // 8 KB   sum of |X|^2 over this block's 8 signals

    const int tid = threadIdx.x;
    const int bi  = blockIdx.x;
    const int b   = bi >> 6;
    const int h   = (bi >> 3) & 7;
    const int eo  = bi & 7;

    for (int k = tid; k < 2048; k += NTHREADS) {
        float2 t = trig[k];
        tw[k] = make_float2(t.x, -t.y);
        eacc[k] = 0.f;
    }
    __syncthreads();

    const float* qb = q + ((size_t)b * 4096 * 512) + (size_t)h * 64 + (size_t)eo * 8;

    for (int p = 0; p < 4; ++p) {
        // load packed pair (e0, e0+1) with bit-reversed order
        for (int i = tid; i < 4096; i += NTHREADS) {
            int r = __brev(i) >> 20;  // 12-bit reversal
            const float* src = qb + (size_t)r * 512 + 2 * p;
            z[i] = make_float2(src[0], src[1]);
        }
        __syncthreads();

        // 12 radix-2 DIT stages
        for (int st = 1; st <= 12; ++st) {
            const int half = 1 << (st - 1);
            for (int t = tid; t < 2048; t += NTHREADS) {
                int grp = t >> (st - 1);
                int j   = t & (half - 1);
                int pos = (grp << st) + j;
                float2 w = tw[j << (12 - st)];
                float2 u = z[pos];
                float2 v = z[pos + half];
                float vr = v.x * w.x - v.y * w.y;
                float vi = v.x * w.y + v.y * w.x;
                z[pos]        = make_float2(u.x + vr, u.y + vi);
                z[pos + half] = make_float2(u.x - vr, u.y - vi);
            }
            __syncthreads();
        }

        // unpack two real spectra; store; accumulate energy
        {
            const int e0 = eo * 8 + 2 * p;
            const size_t s0 = ((size_t)((b * 8 + h) * 64 + e0)) * 2048;
            for (int t = tid; t < 2048; t += NTHREADS) {
                int m = t + 1;
                float2 Za = z[m];
                float2 Zb = z[4096 - m];
                float Xr0 = 0.5f * (Za.x + Zb.x);
                float Xi0 = 0.5f * (Za.y - Zb.y);
                float Xr1 = 0.5f * (Za.y + Zb.y);
                float Xi1 = 0.5f * (Zb.x - Za.x);
                Xout[s0 + t]        = make_float2(Xr0, Xi0);
                Xout[s0 + 2048 + t] = make_float2(Xr1, Xi1);
                eacc[t] += Xr0 * Xr0 + Xi0 * Xi0 + Xr1 * Xr1 + Xi1 * Xi1;
            }
        }
        __syncthreads();  // protect z before next pair's load
    }

    // deterministic reduction: fixed-point u64 atomics (integer adds commute exactly)
    for (int t = tid; t < 2048; t += NTHREADS) {
        unsigned long long v = (unsigned long long)llrintf(eacc[t] * 1048576.0f);  // 2^20
        atomicAdd(&score[t], v);
    }
}

// ---------------- top-64 with jax.lax.top_k semantics (desc, ties -> lower index) ----------------
__global__ __launch_bounds__(1024) void k_topk(const unsigned long long* __restrict__ score,
                                               int* __restrict__ idx) {
    __shared__ unsigned long long s[2048];
    int tid = threadIdx.x;
    for (int t = tid; t < 2048; t += 1024) s[t] = score[t];
    __syncthreads();
    for (int t = tid; t < 2048; t += 1024) {
        unsigned long long my = s[t];
        int rank = 0;
        for (int u = 0; u < 2048; ++u) {
            unsigned long long o = s[u];
            rank += (int)((o > my) || (o == my && u < t));
        }
        if (rank < 64) idx[rank] = t + 1;  // store frequency index m
    }
}

// ---------------- gather + complex projection: Y[b,j,h,f] = sum_e X[b,idx_j,h,e] * W[j,h,e,f] ----
// grid: 512 blocks = (j:64, h:8). Y stored as [b][h][f][j] (j fastest) for the synth kernel.
__global__ __launch_bounds__(256) void k_proj(const float2* __restrict__ X,
                                              const float* __restrict__ wr,
                                              const float* __restrict__ wi,
                                              const int* __restrict__ idx,
                                              float2* __restrict__ Y) {
    __shared__ float2 xs[16 * 64];   // [b][e]  8 KB
    __shared__ float  wrs[64 * 64];  // [e][f] 16 KB
    __shared__ float  wis[64 * 64];  // 16 KB

    const int tid = threadIdx.x;
    const int j = blockIdx.x >> 3;
    const int h = blockIdx.x & 7;
    const int m = idx[j];

    for (int t = tid; t < 1024; t += NTHREADS) {
        int b = t >> 6, e = t & 63;
        xs[t] = X[((size_t)((b * 8 + h) * 64 + e)) * 2048 + (size_t)(m - 1)];
    }
    const float* wrb = wr + ((size_t)(j * 8 + h)) * 4096;
    const float* wib = wi + ((size_t)(j * 8 + h)) * 4096;
    for (int t = tid; t < 4096; t += NTHREADS) { wrs[t] = wrb[t]; wis[t] = wib[t]; }
    __syncthreads();

    const int b  = tid >> 4;   // 0..15
    const int fg = tid & 15;   // 0..15
    for (int fo = 0; fo < 4; ++fo) {
        int f = fg * 4 + fo;
        float yr = 0.f, yi = 0.f;
        for (int e = 0; e < 64; ++e) {
            float2 x = xs[b * 64 + e];
            float a = wrs[e * 64 + f], c = wis[e * 64 + f];
            yr += x.x * a - x.y * c;
            yi += x.x * c + x.y * a;
        }
        Y[((size_t)((b * 8 + h) * 64 + f)) * 64 + j] = make_float2(yr, yi);
    }
}

// ---------------- synthesis: out[b,l,h,f] = (Yr0 + 2*sum_{j=1}^{63} (Yr_j cos - Yi_j sin)) / 4096 -
// grid: 512 blocks = (b:16, h:8, lq:4); threads = f(64) x lg(4); each thread does 256 l values.
__global__ __launch_bounds__(256) void k_synth(const float2* __restrict__ Y,
                                               const float2* __restrict__ trig,
                                               float* __restrict__ out) {
    __shared__ float2 ylds[64][65];  // padded: avoid 32-way conflicts on [f][j] reads (33.3 KB)
    __shared__ float2 tl[4096];      // 32 KB

    const int tid = threadIdx.x;
    const int bi  = blockIdx.x;
    const int b   = bi >> 5;
    const int h   = (bi >> 2) & 7;
    const int lq  = bi & 3;

    const float2* yb = Y + (size_t)(b * 8 + h) * 4096;
    for (int t = tid; t < 4096; t += NTHREADS) {
        ylds[t >> 6][t & 63] = yb[t];
        tl[t] = trig[t];
    }
    __syncthreads();

    const int f  = tid & 63;
    const int lg = tid >> 6;
    const int l0 = lq * 1024 + lg * 256;
    float* ob = out + ((size_t)b * 4096) * 512 + (size_t)h * 64 + f;

    const float y0 = ylds[f][0].x;  // bin-0 imag is ignored by irfft
    const float scale = 2.0f / 4096.0f;

    for (int lc = 0; lc < 256; lc += 8) {
        float acc[8];
#pragma unroll
        for (int i = 0; i < 8; ++i) acc[i] = 0.5f * y0;
        const int lbase = l0 + lc;
        for (int jj = 1; jj < 64; ++jj) {
            float2 y = ylds[f][jj];
            int k = (jj * lbase) & 4095;
#pragma unroll
            for (int i = 0; i < 8; ++i) {
                float2 cs = tl[k];
                acc[i] += y.x * cs.x - y.y * cs.y;
                k = (k + jj) & 4095;
            }
        }
#pragma unroll
        for (int i = 0; i < 8; ++i) {
            ob[(size_t)(lbase + i) * 512] = acc[i] * scale;
        }
    }
}

// ---------------- launch ----------------
extern "C" void kernel_launch(void* const* d_in, const int* in_sizes, int n_in,
                              void* d_out, int out_size, void* d_ws, size_t ws_size,
                              hipStream_t stream) {
    const float* q  = (const float*)d_in[0];
    const float* wr = (const float*)d_in[3];
    const float* wi = (const float*)d_in[4];

    char* ws = (char*)d_ws;
    float2*             trig  = (float2*)(ws + 0);            // 32 KB
    unsigned long long* score = (unsigned long long*)(ws + 32768);  // 16 KB
    int*                idx   = (int*)(ws + 49152);           // 256 B
    float2*             Y     = (float2*)(ws + 65536);        // 4 MB

    // d_out doubles as the spectrum scratch: 8192 signals x 2048 bins x 8 B == out bytes exactly.
    float2* Xs = (float2*)d_out;

    hipMemsetAsync(score, 0, 2048 * sizeof(unsigned long long), stream);
    k_tables<<<16, 256, 0, stream>>>(trig);
    k_fft<<<1024, 256, 0, stream>>>(q, trig, Xs, score);
    k_topk<<<1, 1024, 0, stream>>>(score, idx);
    k_proj<<<512, 256, 0, stream>>>(Xs, wr, wi, idx, Y);
    k_synth<<<512, 256, 0, stream>>>(Y, trig, (float*)d_out);
}

// Round 3
// 743.251 us; speedup vs baseline: 1.3554x; 1.3554x over previous
//
#include <hip/hip_runtime.h>

// Problem constants: B=16, L=4096, H=8, E=64, K=64, F=2049 (rfft bins)
// Only bins m in [1,2048] matter (bin 0 excluded from top-k; out_ft uses slots 0..63).

#define NTHREADS 256

// ---------------- table kernel: trig[k] = (cos, sin)(2*pi*k/4096), f64-accurate ----------------
__global__ void k_tables(float2* __restrict__ trig) {
    int k = blockIdx.x * blockDim.x + threadIdx.x;
    if (k < 4096) {
        double th = (6.283185307179586476925286766559 * (double)k) / 4096.0;
        trig[k] = make_float2((float)cos(th), (float)sin(th));
    }
}

// ---------------- FFT + spectrum store + score accumulation ----------------
// grid: 1024 blocks = (b:16, h:8, eo:8). Each block: 4 complex FFTs covering e = 8*eo .. 8*eo+7
// (two real signals per complex FFT). X[m], m=1..2048 stored to Xout[sig*2048 + (m-1)].
__global__ __launch_bounds__(256) void k_fft(const float* __restrict__ q,
                                             const float2* __restrict__ trig,
                                             float2* __restrict__ Xout,
                                             unsigned long long* __restrict__ score) {
    __shared__ float2 z[4096];     // 32 KB
    __shared__ float2 tw[2048];    // 16 KB  e^{-2pi i k/4096}
    __shared__ float  eacc[2048];  // 8 KB   sum of |X|^2 over this block's 8 signals

    const int tid = threadIdx.x;
    const int bi  = blockIdx.x;
    const int b   = bi >> 6;
    const int h   = (bi >> 3) & 7;
    const int eo  = bi & 7;

    for (int k = tid; k < 2048; k += NTHREADS) {
        float2 t = trig[k];
        tw[k] = make_float2(t.x, -t.y);
        eacc[k] = 0.f;
    }
    __syncthreads();

    const float* qb = q + ((size_t)b * 4096 * 512) + (size_t)h * 64 + (size_t)eo * 8;

    for (int p = 0; p < 4; ++p) {
        // load packed pair (e0, e0+1) with bit-reversed order
        for (int i = tid; i < 4096; i += NTHREADS) {
            int r = __brev(i) >> 20;  // 12-bit reversal
            const float* src = qb + (size_t)r * 512 + 2 * p;
            z[i] = make_float2(src[0], src[1]);
        }
        __syncthreads();

        // 12 radix-2 DIT stages
        for (int st = 1; st <= 12; ++st) {
            const int half = 1 << (st - 1);
            for (int t = tid; t < 2048; t += NTHREADS) {
                int grp = t >> (st - 1);
                int j   = t & (half - 1);
                int pos = (grp << st) + j;
                float2 w = tw[j << (12 - st)];
                float2 u = z[pos];
                float2 v = z[pos + half];
                float vr = v.x * w.x - v.y * w.y;
                float vi = v.x * w.y + v.y * w.x;
                z[pos]        = make_float2(u.x + vr, u.y + vi);
                z[pos + half] = make_float2(u.x - vr, u.y - vi);
            }
            __syncthreads();
        }

        // unpack two real spectra; store; accumulate energy
        {
            const int e0 = eo * 8 + 2 * p;
            const size_t s0 = ((size_t)((b * 8 + h) * 64 + e0)) * 2048;
            for (int t = tid; t < 2048; t += NTHREADS) {
                int m = t + 1;
                float2 Za = z[m];
                float2 Zb = z[4096 - m];
                float Xr0 = 0.5f * (Za.x + Zb.x);
                float Xi0 = 0.5f * (Za.y - Zb.y);
                float Xr1 = 0.5f * (Za.y + Zb.y);
                float Xi1 = 0.5f * (Zb.x - Za.x);
                Xout[s0 + t]        = make_float2(Xr0, Xi0);
                Xout[s0 + 2048 + t] = make_float2(Xr1, Xi1);
                eacc[t] += Xr0 * Xr0 + Xi0 * Xi0 + Xr1 * Xr1 + Xi1 * Xi1;
            }
        }
        __syncthreads();  // protect z before next pair's load
    }

    // deterministic reduction: fixed-point u64 atomics (integer adds commute exactly)
    for (int t = tid; t < 2048; t += NTHREADS) {
        unsigned long long v = (unsigned long long)llrintf(eacc[t] * 1048576.0f);  // 2^20
        atomicAdd(&score[t], v);
    }
}

// ---------------- top-64 with jax.lax.top_k semantics (desc, ties -> lower index) ----------------
__global__ __launch_bounds__(1024) void k_topk(const unsigned long long* __restrict__ score,
                                               int* __restrict__ idx) {
    __shared__ unsigned long long s[2048];
    int tid = threadIdx.x;
    for (int t = tid; t < 2048; t += 1024) s[t] = score[t];
    __syncthreads();
    for (int t = tid; t < 2048; t += 1024) {
        unsigned long long my = s[t];
        int rank = 0;
        for (int u = 0; u < 2048; ++u) {
            unsigned long long o = s[u];
            rank += (int)((o > my) || (o == my && u < t));
        }
        if (rank < 64) idx[rank] = t + 1;  // store frequency index m
    }
}

// ---------------- gather + complex projection: Y[b,j,h,f] = sum_e X[b,idx_j,h,e] * W[j,h,e,f] ----
// grid: 512 blocks = (j:64, h:8). Y stored as [b][j][h*64+f] (hf fastest) for the synth GEMM.
__global__ __launch_bounds__(256) void k_proj(const float2* __restrict__ X,
                                              const float* __restrict__ wr,
                                              const float* __restrict__ wi,
                                              const int* __restrict__ idx,
                                              float2* __restrict__ Y) {
    __shared__ float2 xs[16 * 64];   // [b][e]  8 KB
    __shared__ float  wrs[64 * 64];  // [e][f] 16 KB
    __shared__ float  wis[64 * 64];  // 16 KB

    const int tid = threadIdx.x;
    const int j = blockIdx.x >> 3;
    const int h = blockIdx.x & 7;
    const int m = idx[j];

    for (int t = tid; t < 1024; t += NTHREADS) {
        int b = t >> 6, e = t & 63;
        xs[t] = X[((size_t)((b * 8 + h) * 64 + e)) * 2048 + (size_t)(m - 1)];
    }
    const float* wrb = wr + ((size_t)(j * 8 + h)) * 4096;
    const float* wib = wi + ((size_t)(j * 8 + h)) * 4096;
    for (int t = tid; t < 4096; t += NTHREADS) { wrs[t] = wrb[t]; wis[t] = wib[t]; }
    __syncthreads();

    const int b  = tid >> 4;   // 0..15
    const int fg = tid & 15;   // 0..15
    for (int fo = 0; fo < 4; ++fo) {
        int f = fg * 4 + fo;
        float yr = 0.f, yi = 0.f;
        for (int e = 0; e < 64; ++e) {
            float2 x = xs[b * 64 + e];
            float a = wrs[e * 64 + f], c = wis[e * 64 + f];
            yr += x.x * a - x.y * c;
            yi += x.x * c + x.y * a;
        }
        // [b][j][hf], hf = h*64+f fastest
        Y[((size_t)b * 64 + j) * 512 + (size_t)(h * 64 + f)] = make_float2(yr, yi);
    }
}

// ---------------- synthesis as f32 GEMM: out[b,l,hf] = sum_j A[l,j] (.) Y[b,j,hf] -------------
// A[l,j] = e^{+i 2pi j l / 4096}, generated per-thread by complex rotators (no LDS lookups).
// grid: 2048 blocks = (b:16, hft:4, lt:32). Block tile: 128 l x 128 hf. Thread: 8l x 8hf.
// Thread (r,c): l = lt*128 + r*8 + v (v=0..7); hf = hft*128 + c*2 + (u&1) + (u>>1)*32 (u=0..7).
__global__ __launch_bounds__(256) void k_synth(const float2* __restrict__ Y,
                                               const float2* __restrict__ trig,
                                               float* __restrict__ out) {
    __shared__ float2 ys[64][128];  // 64 KB, pre-scaled: j=0 -> (Yr/N, 0); j>0 -> (2/N)*Y

    const int tid = threadIdx.x;
    const int bi  = blockIdx.x;
    const int b   = bi >> 7;        // 16
    const int hft = (bi >> 5) & 3;  // 4
    const int lt  = bi & 31;        // 32

    const float invN = 1.0f / 4096.0f;
    const float2* yb = Y + (size_t)b * 64 * 512 + (size_t)hft * 128;
    for (int t = tid; t < 64 * 128; t += NTHREADS) {
        int j = t >> 7, cc = t & 127;
        float2 y = yb[(size_t)j * 512 + cc];
        if (j == 0) ys[0][cc] = make_float2(y.x * invN, 0.0f);
        else        ys[j][cc] = make_float2(y.x * (2.0f * invN), y.y * (2.0f * invN));
    }
    __syncthreads();

    const int r = tid >> 4;         // 0..15
    const int c = tid & 15;         // 0..15
    const int l0 = lt * 128 + r * 8;

    // per-row rotators: rot_v(j) = e^{+i 2pi (l0+v) j / 4096}
    float2 rot[8], w[8];
#pragma unroll
    for (int v = 0; v < 8; ++v) {
        w[v] = trig[(l0 + v) & 4095];
        rot[v] = make_float2(1.0f, 0.0f);
    }

    float acc[8][8];
#pragma unroll
    for (int v = 0; v < 8; ++v)
#pragma unroll
        for (int u = 0; u < 8; ++u) acc[v][u] = 0.0f;

    for (int j = 0; j < 64; ++j) {
        float2 yv[8];
#pragma unroll
        for (int u = 0; u < 8; ++u) {
            // bank = (addr/4)%32 = (c*4 + ...) % 32 -> 2-way aliasing (free)
            yv[u] = ys[j][c * 2 + (u & 1) + (u >> 1) * 32];
        }
#pragma unroll
        for (int v = 0; v < 8; ++v) {
            float cx = rot[v].x, sx = rot[v].y;
#pragma unroll
            for (int u = 0; u < 8; ++u) {
                acc[v][u] += cx * yv[u].x - sx * yv[u].y;
            }
        }
        // advance rotators
#pragma unroll
        for (int v = 0; v < 8; ++v) {
            float nx = rot[v].x * w[v].x - rot[v].y * w[v].y;
            float ny = rot[v].x * w[v].y + rot[v].y * w[v].x;
            rot[v] = make_float2(nx, ny);
        }
    }

    // write out: out[(b*4096 + l)*512 + hft*128 + c*2 + (u&1) + (u>>1)*32]
#pragma unroll
    for (int v = 0; v < 8; ++v) {
        float* ob = out + ((size_t)(b * 4096 + l0 + v)) * 512 + (size_t)hft * 128;
#pragma unroll
        for (int k = 0; k < 4; ++k) {
            float2 st = make_float2(acc[v][2 * k], acc[v][2 * k + 1]);
            *(float2*)(ob + k * 32 + c * 2) = st;
        }
    }
}

// ---------------- launch ----------------
extern "C" void kernel_launch(void* const* d_in, const int* in_sizes, int n_in,
                              void* d_out, int out_size, void* d_ws, size_t ws_size,
                              hipStream_t stream) {
    const float* q  = (const float*)d_in[0];
    const float* wr = (const float*)d_in[3];
    const float* wi = (const float*)d_in[4];

    char* ws = (char*)d_ws;
    float2*             trig  = (float2*)(ws + 0);            // 32 KB
    unsigned long long* score = (unsigned long long*)(ws + 32768);  // 16 KB
    int*                idx   = (int*)(ws + 49152);           // 256 B
    float2*             Y     = (float2*)(ws + 65536);        // 4 MB

    // d_out doubles as the spectrum scratch: 8192 signals x 2048 bins x 8 B == out bytes exactly.
    float2* Xs = (float2*)d_out;

    hipMemsetAsync(score, 0, 2048 * sizeof(unsigned long long), stream);
    k_tables<<<16, 256, 0, stream>>>(trig);
    k_fft<<<1024, 256, 0, stream>>>(q, trig, Xs, score);
    k_topk<<<1, 1024, 0, stream>>>(score, idx);
    k_proj<<<512, 256, 0, stream>>>(Xs, wr, wi, idx, Y);
    k_synth<<<2048, 256, 0, stream>>>(Y, trig, (float*)d_out);  // 2048 = (b:16, hft:4, lt:32)
}

// Round 4
// 548.625 us; speedup vs baseline: 1.8363x; 1.3548x over previous
//
#include <hip/hip_runtime.h>

// Problem constants: B=16, L=4096, H=8, E=64, K=64, F=2049 (rfft bins)
// Only bins m in [1,2048] matter (bin 0 excluded from top-k; out_ft uses slots 0..63).

#define NTHREADS 256

// ---------------- table kernel: trig[k] = (cos, sin)(2*pi*k/4096), f64-accurate ----------------
__global__ void k_tables(float2* __restrict__ trig) {
    int k = blockIdx.x * blockDim.x + threadIdx.x;
    if (k < 4096) {
        double th = (6.283185307179586476925286766559 * (double)k) / 4096.0;
        trig[k] = make_float2((float)cos(th), (float)sin(th));
    }
}

// ---------------- transpose + bit-reversal: q[b,l,h,e] -> T[(b,h,eo)][p][j] (float2) -----------
// T[bi][p][j] = ( x_{e0}[rev12(j)], x_{e0+1}[rev12(j)] ), e0 = eo*8+2p, region = 128KB per bi.
// Block (b:16, h:8, c4:16): rows l = c4 + 16t (t=0..255). rev12(l) = rev4(c4)*256 + rev8(t):
// destination runs are contiguous 256-element blocks -> fully coalesced float4 stores.
__global__ __launch_bounds__(256) void k_xpose(const float* __restrict__ q,
                                               float2* __restrict__ T) {
    __shared__ float tile[256][65];  // padded (+1): write 2-way, read 4-way conflicts only

    const int tid = threadIdx.x;
    const int bi  = blockIdx.x;
    const int b   = bi >> 7;
    const int h   = (bi >> 4) & 7;
    const int c4  = bi & 15;

    // coalesced read: per row, 64 floats (256B, 256B-aligned) via 16 float4s
    const float* qb = q + ((size_t)b * 4096 * 512) + (size_t)h * 64;
    for (int f = tid; f < 4096; f += NTHREADS) {
        int t = f >> 4, e4 = f & 15;
        const float4 v = *(const float4*)(qb + (size_t)(c4 + 16 * t) * 512 + e4 * 4);
        tile[t][e4 * 4 + 0] = v.x;
        tile[t][e4 * 4 + 1] = v.y;
        tile[t][e4 * 4 + 2] = v.z;
        tile[t][e4 * 4 + 3] = v.w;
    }
    __syncthreads();

    // write: combos (eo:8, p:4). float4 = dest j' pair (2m, 2m+1), m = 64r + lane:
    //   t(2m) = rev8(2m) = 2*rev6(lane) + r ; t(2m+1) = t(2m) + 128
    const int wave = tid >> 6, lane = tid & 63;
    const int rl  = __brev(lane) >> 26;  // rev6(lane)
    const int r4c = __brev(c4) >> 28;    // rev4(c4)
    for (int cc = wave; cc < 32; cc += 4) {
        int eo = cc >> 2, p = cc & 3;
        int col0 = eo * 8 + 2 * p;
        float2* dst = T + ((size_t)((b * 8 + h) * 8 + eo)) * 16384 + (size_t)p * 4096
                        + (size_t)r4c * 256;
#pragma unroll
        for (int r = 0; r < 2; ++r) {
            int ta = 2 * rl + r;
            int tb = ta + 128;
            float4 o;
            o.x = tile[ta][col0]; o.y = tile[ta][col0 + 1];
            o.z = tile[tb][col0]; o.w = tile[tb][col0 + 1];
            *(float4*)(dst + 2 * (64 * r + lane)) = o;  // 16B/lane, lane-contiguous 1KB runs
        }
    }
}

// ---------------- FFT + spectrum store + score accumulation ----------------
// grid: 1024 blocks = bi = (b*8+h)*8+eo. Reads its T region IN-PLACE from Xout buffer:
// pair plane p = Xout[bi*16384 + p*4096 .. +4096) (float2), fully loaded to LDS before the
// spectrum for signals e0=2p,2p+1 overwrites the exact same 32KB region.
__global__ __launch_bounds__(256) void k_fft(const float2* __restrict__ trig,
                                             float2* __restrict__ Xout,
                                             unsigned long long* __restrict__ score) {
    __shared__ float2 z[4096];     // 32 KB
    __shared__ float2 tw[2048];    // 16 KB  e^{-2pi i k/4096}
    __shared__ float  eacc[2048];  // 8 KB

    const int tid = threadIdx.x;
    const int bi  = blockIdx.x;

    for (int k = tid; k < 2048; k += NTHREADS) {
        float2 t = trig[k];
        tw[k] = make_float2(t.x, -t.y);
        eacc[k] = 0.f;
    }
    __syncthreads();

    for (int p = 0; p < 4; ++p) {
        // coalesced linear load of the (already bit-reversed) pair plane
        const float2* plane = Xout + (size_t)bi * 16384 + (size_t)p * 4096;
        for (int i = tid; i < 2048; i += NTHREADS) {
            float4 v = *(const float4*)(plane + 2 * i);
            z[2 * i]     = make_float2(v.x, v.y);
            z[2 * i + 1] = make_float2(v.z, v.w);
        }
        __syncthreads();

        // 12 radix-2 DIT stages
        for (int st = 1; st <= 12; ++st) {
            const int half = 1 << (st - 1);
            for (int t = tid; t < 2048; t += NTHREADS) {
                int grp = t >> (st - 1);
                int j   = t & (half - 1);
                int pos = (grp << st) + j;
                float2 w = tw[j << (12 - st)];
                float2 u = z[pos];
                float2 v = z[pos + half];
                float vr = v.x * w.x - v.y * w.y;
                float vi = v.x * w.y + v.y * w.x;
                z[pos]        = make_float2(u.x + vr, u.y + vi);
                z[pos + half] = make_float2(u.x - vr, u.y - vi);
            }
            __syncthreads();
        }

        // unpack two real spectra; store (overwrites this pair's own plane); accumulate energy
        {
            const size_t s0 = (size_t)bi * 16384 + (size_t)p * 4096;  // = signal (bi*8+2p) * 2048
            for (int t = tid; t < 2048; t += NTHREADS) {
                int m = t + 1;
                float2 Za = z[m];
                float2 Zb = z[4096 - m];
                float Xr0 = 0.5f * (Za.x + Zb.x);
                float Xi0 = 0.5f * (Za.y - Zb.y);
                float Xr1 = 0.5f * (Za.y + Zb.y);
                float Xi1 = 0.5f * (Zb.x - Za.x);
                Xout[s0 + t]        = make_float2(Xr0, Xi0);
                Xout[s0 + 2048 + t] = make_float2(Xr1, Xi1);
                eacc[t] += Xr0 * Xr0 + Xi0 * Xi0 + Xr1 * Xr1 + Xi1 * Xi1;
            }
        }
        __syncthreads();  // protect z before next pair's load
    }

    // deterministic reduction: fixed-point u64 atomics (integer adds commute exactly)
    for (int t = tid; t < 2048; t += NTHREADS) {
        unsigned long long v = (unsigned long long)llrintf(eacc[t] * 1048576.0f);  // 2^20
        atomicAdd(&score[t], v);
    }
}

// ---------------- top-64 with jax.lax.top_k semantics (desc, ties -> lower index) ----------------
__global__ __launch_bounds__(1024) void k_topk(const unsigned long long* __restrict__ score,
                                               int* __restrict__ idx) {
    __shared__ unsigned long long s[2048];
    int tid = threadIdx.x;
    for (int t = tid; t < 2048; t += 1024) s[t] = score[t];
    __syncthreads();
    for (int t = tid; t < 2048; t += 1024) {
        unsigned long long my = s[t];
        int rank = 0;
        for (int u = 0; u < 2048; ++u) {
            unsigned long long o = s[u];
            rank += (int)((o > my) || (o == my && u < t));
        }
        if (rank < 64) idx[rank] = t + 1;  // store frequency index m
    }
}

// ---------------- gather + complex projection: Y[b,j,h,f] = sum_e X[b,idx_j,h,e] * W[j,h,e,f] ----
// grid: 512 blocks = (j:64, h:8). Y stored as [b][j][h*64+f] (hf fastest) for the synth GEMM.
__global__ __launch_bounds__(256) void k_proj(const float2* __restrict__ X,
                                              const float* __restrict__ wr,
                                              const float* __restrict__ wi,
                                              const int* __restrict__ idx,
                                              float2* __restrict__ Y) {
    __shared__ float2 xs[16 * 64];   // [b][e]  8 KB
    __shared__ float  wrs[64 * 64];  // [e][f] 16 KB
    __shared__ float  wis[64 * 64];  // 16 KB

    const int tid = threadIdx.x;
    const int j = blockIdx.x >> 3;
    const int h = blockIdx.x & 7;
    const int m = idx[j];

    for (int t = tid; t < 1024; t += NTHREADS) {
        int b = t >> 6, e = t & 63;
        xs[t] = X[((size_t)((b * 8 + h) * 64 + e)) * 2048 + (size_t)(m - 1)];
    }
    const float* wrb = wr + ((size_t)(j * 8 + h)) * 4096;
    const float* wib = wi + ((size_t)(j * 8 + h)) * 4096;
    for (int t = tid; t < 4096; t += NTHREADS) { wrs[t] = wrb[t]; wis[t] = wib[t]; }
    __syncthreads();

    const int b  = tid >> 4;   // 0..15
    const int fg = tid & 15;   // 0..15
    for (int fo = 0; fo < 4; ++fo) {
        int f = fg * 4 + fo;
        float yr = 0.f, yi = 0.f;
        for (int e = 0; e < 64; ++e) {
            float2 x = xs[b * 64 + e];
            float a = wrs[e * 64 + f], c = wis[e * 64 + f];
            yr += x.x * a - x.y * c;
            yi += x.x * c + x.y * a;
        }
        // [b][j][hf], hf = h*64+f fastest
        Y[((size_t)b * 64 + j) * 512 + (size_t)(h * 64 + f)] = make_float2(yr, yi);
    }
}

// ---------------- synthesis as f32 GEMM: out[b,l,hf] = sum_j A[l,j] (.) Y[b,j,hf] -------------
// A[l,j] = e^{+i 2pi j l / 4096}, generated per-thread by complex rotators (no LDS lookups).
// grid: 2048 blocks = (b:16, hft:4, lt:32). Block tile: 128 l x 128 hf. Thread: 8l x 8hf.
__global__ __launch_bounds__(256) void k_synth(const float2* __restrict__ Y,
                                               const float2* __restrict__ trig,
                                               float* __restrict__ out) {
    __shared__ float2 ys[64][128];  // 64 KB, pre-scaled: j=0 -> (Yr/N, 0); j>0 -> (2/N)*Y

    const int tid = threadIdx.x;
    const int bi  = blockIdx.x;
    const int b   = bi >> 7;        // 16
    const int hft = (bi >> 5) & 3;  // 4
    const int lt  = bi & 31;        // 32

    const float invN = 1.0f / 4096.0f;
    const float2* yb = Y + (size_t)b * 64 * 512 + (size_t)hft * 128;
    for (int t = tid; t < 64 * 128; t += NTHREADS) {
        int j = t >> 7, cc = t & 127;
        float2 y = yb[(size_t)j * 512 + cc];
        if (j == 0) ys[0][cc] = make_float2(y.x * invN, 0.0f);
        else        ys[j][cc] = make_float2(y.x * (2.0f * invN), y.y * (2.0f * invN));
    }
    __syncthreads();

    const int r = tid >> 4;         // 0..15
    const int c = tid & 15;         // 0..15
    const int l0 = lt * 128 + r * 8;

    float2 rot[8], w[8];
#pragma unroll
    for (int v = 0; v < 8; ++v) {
        w[v] = trig[(l0 + v) & 4095];
        rot[v] = make_float2(1.0f, 0.0f);
    }

    float acc[8][8];
#pragma unroll
    for (int v = 0; v < 8; ++v)
#pragma unroll
        for (int u = 0; u < 8; ++u) acc[v][u] = 0.0f;

    for (int j = 0; j < 64; ++j) {
        float2 yv[8];
#pragma unroll
        for (int u = 0; u < 8; ++u) {
            yv[u] = ys[j][c * 2 + (u & 1) + (u >> 1) * 32];
        }
#pragma unroll
        for (int v = 0; v < 8; ++v) {
            float cx = rot[v].x, sx = rot[v].y;
#pragma unroll
            for (int u = 0; u < 8; ++u) {
                acc[v][u] += cx * yv[u].x - sx * yv[u].y;
            }
        }
#pragma unroll
        for (int v = 0; v < 8; ++v) {
            float nx = rot[v].x * w[v].x - rot[v].y * w[v].y;
            float ny = rot[v].x * w[v].y + rot[v].y * w[v].x;
            rot[v] = make_float2(nx, ny);
        }
    }

#pragma unroll
    for (int v = 0; v < 8; ++v) {
        float* ob = out + ((size_t)(b * 4096 + l0 + v)) * 512 + (size_t)hft * 128;
#pragma unroll
        for (int k = 0; k < 4; ++k) {
            float2 st = make_float2(acc[v][2 * k], acc[v][2 * k + 1]);
            *(float2*)(ob + k * 32 + c * 2) = st;
        }
    }
}

// ---------------- launch ----------------
extern "C" void kernel_launch(void* const* d_in, const int* in_sizes, int n_in,
                              void* d_out, int out_size, void* d_ws, size_t ws_size,
                              hipStream_t stream) {
    const float* q  = (const float*)d_in[0];
    const float* wr = (const float*)d_in[3];
    const float* wi = (const float*)d_in[4];

    char* ws = (char*)d_ws;
    float2*             trig  = (float2*)(ws + 0);                  // 32 KB
    unsigned long long* score = (unsigned long long*)(ws + 32768);  // 16 KB
    int*                idx   = (int*)(ws + 49152);                 // 256 B
    float2*             Y     = (float2*)(ws + 65536);              // 4 MB

    // d_out triples as: transposed-q scratch T -> spectrum Xout (in-place) -> final output.
    float2* Xs = (float2*)d_out;

    hipMemsetAsync(score, 0, 2048 * sizeof(unsigned long long), stream);
    k_tables<<<16, 256, 0, stream>>>(trig);
    k_xpose<<<2048, 256, 0, stream>>>(q, Xs);          // (b:16, h:8, c4:16)
    k_fft<<<1024, 256, 0, stream>>>(trig, Xs, score);  // in-place T -> spectra
    k_topk<<<1, 1024, 0, stream>>>(score, idx);
    k_proj<<<512, 256, 0, stream>>>(Xs, wr, wi, idx, Y);
    k_synth<<<2048, 256, 0, stream>>>(Y, trig, (float*)d_out);  // (b:16, hft:4, lt:32)
}

// Round 5
// 454.379 us; speedup vs baseline: 2.2171x; 1.2074x over previous
//
#include <hip/hip_runtime.h>

// Problem constants: B=16, L=4096, H=8, E=64, K=64, F=2049 (rfft bins)
// Only bins m in [1,2048] matter (bin 0 excluded from top-k; out_ft uses slots 0..63).

#define NTHREADS 256

__device__ inline float2 f2add(float2 a, float2 b) { return make_float2(a.x + b.x, a.y + b.y); }
__device__ inline float2 f2sub(float2 a, float2 b) { return make_float2(a.x - b.x, a.y - b.y); }
// complex mul, exactly 4 VALU (mul, fma, mul, fma)
__device__ inline float2 cmulf(float2 a, float2 b) {
    return make_float2(__builtin_fmaf(a.x, b.x, -(a.y * b.y)),
                       __builtin_fmaf(a.x, b.y,  a.y * b.x));
}

// radix-8 DIT butterfly on 8 points spaced h apart (3 stages in registers).
// wA = tw[j<<(12-st)], wB = tw[j<<(11-st)], wC = tw[j<<(10-st)].
__device__ inline void radix8(float2& u0, float2& u1, float2& u2, float2& u3,
                              float2& u4, float2& u5, float2& u6, float2& u7,
                              float2 wA, float2 wB, float2 wC) {
    float2 t1 = cmulf(wA, u1), t3 = cmulf(wA, u3), t5 = cmulf(wA, u5), t7 = cmulf(wA, u7);
    float2 a0 = f2add(u0, t1), a1 = f2sub(u0, t1);
    float2 a2 = f2add(u2, t3), a3 = f2sub(u2, t3);
    float2 a4 = f2add(u4, t5), a5 = f2sub(u4, t5);
    float2 a6 = f2add(u6, t7), a7 = f2sub(u6, t7);
    float2 s2 = cmulf(wB, a2), s3 = cmulf(wB, a3);
    float2 s6 = cmulf(wB, a6), s7 = cmulf(wB, a7);
    float2 b0 = f2add(a0, s2), b2 = f2sub(a0, s2);
    float2 b1 = make_float2(a1.x + s3.y, a1.y - s3.x);   // a1 + (-i)s3
    float2 b3 = make_float2(a1.x - s3.y, a1.y + s3.x);   // a1 - (-i)s3
    float2 b4 = f2add(a4, s6), b6 = f2sub(a4, s6);
    float2 b5 = make_float2(a5.x + s7.y, a5.y - s7.x);
    float2 b7 = make_float2(a5.x - s7.y, a5.y + s7.x);
    const float2 C8 = make_float2(0.70710678118654752f, -0.70710678118654752f);  // e^{-i pi/4}
    float2 wC1 = cmulf(wC, C8);
    float2 r4 = cmulf(wC, b4);
    float2 r5 = cmulf(wC1, b5);
    float2 r6t = cmulf(wC, b6);  float2 r6 = make_float2(r6t.y, -r6t.x);   // -i * wC * b6
    float2 r7t = cmulf(wC1, b7); float2 r7 = make_float2(r7t.y, -r7t.x);   // e^{-3i pi/4} wC b7
    u0 = f2add(b0, r4); u4 = f2sub(b0, r4);
    u1 = f2add(b1, r5); u5 = f2sub(b1, r5);
    u2 = f2add(b2, r6); u6 = f2sub(b2, r6);
    u3 = f2add(b3, r7); u7 = f2sub(b3, r7);
}

// ---------------- table kernel: trig[k] = (cos, sin)(2*pi*k/4096), f64-accurate ----------------
__global__ void k_tables(float2* __restrict__ trig) {
    int k = blockIdx.x * blockDim.x + threadIdx.x;
    if (k < 4096) {
        double th = (6.283185307179586476925286766559 * (double)k) / 4096.0;
        trig[k] = make_float2((float)cos(th), (float)sin(th));
    }
}

// ---------------- transpose + bit-reversal: q[b,l,h,e] -> T[(b,h,eo)][p][j] (float2) -----------
// T[bi][p][j] = ( x_{e0}[rev12(j)], x_{e0+1}[rev12(j)] ), e0 = eo*8+2p, region = 128KB per bi.
// Block (b:16, h:8, c4:16): rows l = c4 + 16t (t=0..255). rev12(l) = rev4(c4)*256 + rev8(t):
// destination runs are contiguous 256-element blocks -> fully coalesced float4 stores.
__global__ __launch_bounds__(256) void k_xpose(const float* __restrict__ q,
                                               float2* __restrict__ T) {
    __shared__ float tile[256][65];  // padded (+1)

    const int tid = threadIdx.x;
    const int bi  = blockIdx.x;
    const int b   = bi >> 7;
    const int h   = (bi >> 4) & 7;
    const int c4  = bi & 15;

    const float* qb = q + ((size_t)b * 4096 * 512) + (size_t)h * 64;
    for (int f = tid; f < 4096; f += NTHREADS) {
        int t = f >> 4, e4 = f & 15;
        const float4 v = *(const float4*)(qb + (size_t)(c4 + 16 * t) * 512 + e4 * 4);
        tile[t][e4 * 4 + 0] = v.x;
        tile[t][e4 * 4 + 1] = v.y;
        tile[t][e4 * 4 + 2] = v.z;
        tile[t][e4 * 4 + 3] = v.w;
    }
    __syncthreads();

    const int wave = tid >> 6, lane = tid & 63;
    const int rl  = __brev(lane) >> 26;  // rev6(lane)
    const int r4c = __brev(c4) >> 28;    // rev4(c4)
    for (int cc = wave; cc < 32; cc += 4) {
        int eo = cc >> 2, p = cc & 3;
        int col0 = eo * 8 + 2 * p;
        float2* dst = T + ((size_t)((b * 8 + h) * 8 + eo)) * 16384 + (size_t)p * 4096
                        + (size_t)r4c * 256;
#pragma unroll
        for (int r = 0; r < 2; ++r) {
            int ta = 2 * rl + r;
            int tb = ta + 128;
            float4 o;
            o.x = tile[ta][col0]; o.y = tile[ta][col0 + 1];
            o.z = tile[tb][col0]; o.w = tile[tb][col0 + 1];
            *(float4*)(dst + 2 * (64 * r + lane)) = o;
        }
    }
}

// ---------------- FFT (4 x radix-8 passes) + spectrum store + score accumulation ----------------
// grid: 1024 blocks = bi = (b*8+h)*8+eo. Reads its T region IN-PLACE from Xout buffer:
// pair plane p = Xout[bi*16384 + p*4096 .. +4096) (float2), fully loaded before the spectrum
// for signals e0=2p,2p+1 overwrites the exact same 32KB region.
__global__ __launch_bounds__(256) void k_fft(const float2* __restrict__ trig,
                                             float2* __restrict__ Xout,
                                             unsigned long long* __restrict__ score) {
    __shared__ float2 z[4096];     // 32 KB
    __shared__ float2 tw[2048];    // 16 KB  e^{-2pi i k/4096}
    __shared__ float  eacc[2048];  // 8 KB

    const int tid = threadIdx.x;
    const int bi  = blockIdx.x;

    for (int k = tid; k < 2048; k += NTHREADS) {
        float2 t = trig[k];
        tw[k] = make_float2(t.x, -t.y);
        eacc[k] = 0.f;
    }
    __syncthreads();

    const float2 ONE = make_float2(1.0f, 0.0f);

    for (int p = 0; p < 4; ++p) {
        const float2* plane = Xout + (size_t)bi * 16384 + (size_t)p * 4096;

        // pass 0 (stages 1-3, h=1, all twiddles unit -> constant-folded):
        // load 8 contiguous (bit-reversed order) points, radix-8 in regs, store to LDS.
        for (int t = tid; t < 512; t += NTHREADS) {
            const float4 v01 = *(const float4*)(plane + 8 * t);
            const float4 v23 = *(const float4*)(plane + 8 * t + 2);
            const float4 v45 = *(const float4*)(plane + 8 * t + 4);
            const float4 v67 = *(const float4*)(plane + 8 * t + 6);
            float2 u0 = make_float2(v01.x, v01.y), u1 = make_float2(v01.z, v01.w);
            float2 u2 = make_float2(v23.x, v23.y), u3 = make_float2(v23.z, v23.w);
            float2 u4 = make_float2(v45.x, v45.y), u5 = make_float2(v45.z, v45.w);
            float2 u6 = make_float2(v67.x, v67.y), u7 = make_float2(v67.z, v67.w);
            radix8(u0, u1, u2, u3, u4, u5, u6, u7, ONE, ONE, ONE);
            z[8 * t + 0] = u0; z[8 * t + 1] = u1; z[8 * t + 2] = u2; z[8 * t + 3] = u3;
            z[8 * t + 4] = u4; z[8 * t + 5] = u5; z[8 * t + 6] = u6; z[8 * t + 7] = u7;
        }
        __syncthreads();

        // passes 1..3: stages (4,5,6), (7,8,9), (10,11,12); h = 8, 64, 512
#pragma unroll
        for (int p8 = 1; p8 <= 3; ++p8) {
            const int st = 1 + 3 * p8;
            const int h  = 1 << (st - 1);
            for (int t = tid; t < 512; t += NTHREADS) {
                const int j = t & (h - 1);
                const int g = t >> (st - 1);
                const int i0 = (g << (st + 2)) + j;
                float2 u0 = z[i0],         u1 = z[i0 + h],     u2 = z[i0 + 2 * h], u3 = z[i0 + 3 * h];
                float2 u4 = z[i0 + 4 * h], u5 = z[i0 + 5 * h], u6 = z[i0 + 6 * h], u7 = z[i0 + 7 * h];
                const float2 wA = tw[j << (12 - st)];
                const float2 wB = tw[j << (11 - st)];
                const float2 wC = tw[j << (10 - st)];
                radix8(u0, u1, u2, u3, u4, u5, u6, u7, wA, wB, wC);
                z[i0]         = u0; z[i0 + h]     = u1; z[i0 + 2 * h] = u2; z[i0 + 3 * h] = u3;
                z[i0 + 4 * h] = u4; z[i0 + 5 * h] = u5; z[i0 + 6 * h] = u6; z[i0 + 7 * h] = u7;
            }
            __syncthreads();
        }

        // unpack two real spectra; store (overwrites this pair's own plane); accumulate energy
        {
            const size_t s0 = (size_t)bi * 16384 + (size_t)p * 4096;  // = signal (bi*8+2p) * 2048
            for (int t = tid; t < 2048; t += NTHREADS) {
                int m = t + 1;
                float2 Za = z[m];
                float2 Zb = z[4096 - m];
                float Xr0 = 0.5f * (Za.x + Zb.x);
                float Xi0 = 0.5f * (Za.y - Zb.y);
                float Xr1 = 0.5f * (Za.y + Zb.y);
                float Xi1 = 0.5f * (Zb.x - Za.x);
                Xout[s0 + t]        = make_float2(Xr0, Xi0);
                Xout[s0 + 2048 + t] = make_float2(Xr1, Xi1);
                eacc[t] += Xr0 * Xr0 + Xi0 * Xi0 + Xr1 * Xr1 + Xi1 * Xi1;
            }
        }
        __syncthreads();  // protect z before next pair's load
    }

    // deterministic reduction: fixed-point u64 atomics (integer adds commute exactly)
    for (int t = tid; t < 2048; t += NTHREADS) {
        unsigned long long v = (unsigned long long)llrintf(eacc[t] * 1048576.0f);  // 2^20
        atomicAdd(&score[t], v);
    }
}

// ---------------- top-64 with jax.lax.top_k semantics (desc, ties -> lower index) ----------------
__global__ __launch_bounds__(1024) void k_topk(const unsigned long long* __restrict__ score,
                                               int* __restrict__ idx) {
    __shared__ unsigned long long s[2048];
    int tid = threadIdx.x;
    for (int t = tid; t < 2048; t += 1024) s[t] = score[t];
    __syncthreads();
    for (int t = tid; t < 2048; t += 1024) {
        unsigned long long my = s[t];
        int rank = 0;
        for (int u = 0; u < 2048; ++u) {
            unsigned long long o = s[u];
            rank += (int)((o > my) || (o == my && u < t));
        }
        if (rank < 64) idx[rank] = t + 1;  // store frequency index m
    }
}

// ---------------- gather + complex projection: Y[b,j,h,f] = sum_e X[b,idx_j,h,e] * W[j,h,e,f] ----
// grid: 512 blocks = (j:64, h:8). Y stored as [b][j][h*64+f] (hf fastest) for the synth GEMM.
__global__ __launch_bounds__(256) void k_proj(const float2* __restrict__ X,
                                              const float* __restrict__ wr,
                                              const float* __restrict__ wi,
                                              const int* __restrict__ idx,
                                              float2* __restrict__ Y) {
    __shared__ float2 xs[16 * 64];   // [b][e]  8 KB
    __shared__ float  wrs[64 * 64];  // [e][f] 16 KB
    __shared__ float  wis[64 * 64];  // 16 KB

    const int tid = threadIdx.x;
    const int j = blockIdx.x >> 3;
    const int h = blockIdx.x & 7;
    const int m = idx[j];

    for (int t = tid; t < 1024; t += NTHREADS) {
        int b = t >> 6, e = t & 63;
        xs[t] = X[((size_t)((b * 8 + h) * 64 + e)) * 2048 + (size_t)(m - 1)];
    }
    const float* wrb = wr + ((size_t)(j * 8 + h)) * 4096;
    const float* wib = wi + ((size_t)(j * 8 + h)) * 4096;
    for (int t = tid; t < 4096; t += NTHREADS) { wrs[t] = wrb[t]; wis[t] = wib[t]; }
    __syncthreads();

    const int b  = tid >> 4;   // 0..15
    const int fg = tid & 15;   // 0..15
    for (int fo = 0; fo < 4; ++fo) {
        int f = fg * 4 + fo;
        float yr = 0.f, yi = 0.f;
        for (int e = 0; e < 64; ++e) {
            float2 x = xs[b * 64 + e];
            float a = wrs[e * 64 + f], c = wis[e * 64 + f];
            yr = __builtin_fmaf(x.x, a, yr); yr = __builtin_fmaf(-x.y, c, yr);
            yi = __builtin_fmaf(x.x, c, yi); yi = __builtin_fmaf( x.y, a, yi);
        }
        Y[((size_t)b * 64 + j) * 512 + (size_t)(h * 64 + f)] = make_float2(yr, yi);
    }
}

// ---------------- synthesis as f32 GEMM: out[b,l,hf] = sum_j A[l,j] (.) Y[b,j,hf] -------------
// A[l,j] = e^{+i 2pi j l / 4096}, generated per-thread by complex rotators (no LDS lookups).
// grid: 2048 blocks = (b:16, hft:4, lt:32). Block tile: 128 l x 128 hf. Thread: 8l x 8hf.
__global__ __launch_bounds__(256) void k_synth(const float2* __restrict__ Y,
                                               const float2* __restrict__ trig,
                                               float* __restrict__ out) {
    __shared__ float2 ys[64][128];  // 64 KB, pre-scaled: j=0 -> (Yr/N, 0); j>0 -> (2/N)*Y

    const int tid = threadIdx.x;
    const int bi  = blockIdx.x;
    const int b   = bi >> 7;        // 16
    const int hft = (bi >> 5) & 3;  // 4
    const int lt  = bi & 31;        // 32

    const float invN = 1.0f / 4096.0f;
    const float2* yb = Y + (size_t)b * 64 * 512 + (size_t)hft * 128;
    for (int t = tid; t < 64 * 128; t += NTHREADS) {
        int j = t >> 7, cc = t & 127;
        float2 y = yb[(size_t)j * 512 + cc];
        if (j == 0) ys[0][cc] = make_float2(y.x * invN, 0.0f);
        else        ys[j][cc] = make_float2(y.x * (2.0f * invN), y.y * (2.0f * invN));
    }
    __syncthreads();

    const int r = tid >> 4;         // 0..15
    const int c = tid & 15;         // 0..15
    const int l0 = lt * 128 + r * 8;

    float2 rot[8], w[8];
#pragma unroll
    for (int v = 0; v < 8; ++v) {
        w[v] = trig[(l0 + v) & 4095];
        rot[v] = make_float2(1.0f, 0.0f);
    }

    float acc[8][8];
#pragma unroll
    for (int v = 0; v < 8; ++v)
#pragma unroll
        for (int u = 0; u < 8; ++u) acc[v][u] = 0.0f;

    for (int j = 0; j < 64; ++j) {
        float2 yv[8];
#pragma unroll
        for (int u = 0; u < 8; ++u) {
            yv[u] = ys[j][c * 2 + (u & 1) + (u >> 1) * 32];
        }
#pragma unroll
        for (int v = 0; v < 8; ++v) {
            const float cx = rot[v].x, sx = rot[v].y;
#pragma unroll
            for (int u = 0; u < 8; ++u) {
                float a = acc[v][u];
                a = __builtin_fmaf(cx, yv[u].x, a);       // two fused chains, 2 VALU/MAC
                a = __builtin_fmaf(-sx, yv[u].y, a);
                acc[v][u] = a;
            }
        }
#pragma unroll
        for (int v = 0; v < 8; ++v) {
            float nx = __builtin_fmaf(rot[v].x, w[v].x, -(rot[v].y * w[v].y));
            float ny = __builtin_fmaf(rot[v].x, w[v].y,  (rot[v].y * w[v].x));
            rot[v] = make_float2(nx, ny);
        }
    }

#pragma unroll
    for (int v = 0; v < 8; ++v) {
        float* ob = out + ((size_t)(b * 4096 + l0 + v)) * 512 + (size_t)hft * 128;
#pragma unroll
        for (int k = 0; k < 4; ++k) {
            float2 st = make_float2(acc[v][2 * k], acc[v][2 * k + 1]);
            *(float2*)(ob + k * 32 + c * 2) = st;
        }
    }
}

// ---------------- launch ----------------
extern "C" void kernel_launch(void* const* d_in, const int* in_sizes, int n_in,
                              void* d_out, int out_size, void* d_ws, size_t ws_size,
                              hipStream_t stream) {
    const float* q  = (const float*)d_in[0];
    const float* wr = (const float*)d_in[3];
    const float* wi = (const float*)d_in[4];

    char* ws = (char*)d_ws;
    float2*             trig  = (float2*)(ws + 0);                  // 32 KB
    unsigned long long* score = (unsigned long long*)(ws + 32768);  // 16 KB
    int*                idx   = (int*)(ws + 49152);                 // 256 B
    float2*             Y     = (float2*)(ws + 65536);              // 4 MB

    // d_out triples as: transposed-q scratch T -> spectrum Xout (in-place) -> final output.
    float2* Xs = (float2*)d_out;

    hipMemsetAsync(score, 0, 2048 * sizeof(unsigned long long), stream);
    k_tables<<<16, 256, 0, stream>>>(trig);
    k_xpose<<<2048, 256, 0, stream>>>(q, Xs);          // (b:16, h:8, c4:16)
    k_fft<<<1024, 256, 0, stream>>>(trig, Xs, score);  // in-place T -> spectra
    k_topk<<<1, 1024, 0, stream>>>(score, idx);
    k_proj<<<512, 256, 0, stream>>>(Xs, wr, wi, idx, Y);
    k_synth<<<2048, 256, 0, stream>>>(Y, trig, (float*)d_out);  // (b:16, hft:4, lt:32)
}

// Round 6
// 348.447 us; speedup vs baseline: 2.8912x; 1.3040x over previous
//
#include <hip/hip_runtime.h>

// Problem constants: B=16, L=4096, H=8, E=64, K=64, F=2049 (rfft bins)
// Only bins m in [1,2048] matter (bin 0 excluded from top-k; out_ft uses slots 0..63).

#define NTHREADS 256

__device__ inline float2 f2add(float2 a, float2 b) { return make_float2(a.x + b.x, a.y + b.y); }
__device__ inline float2 f2sub(float2 a, float2 b) { return make_float2(a.x - b.x, a.y - b.y); }
// complex mul, exactly 4 VALU (mul, fma, mul, fma)
__device__ inline float2 cmulf(float2 a, float2 b) {
    return make_float2(__builtin_fmaf(a.x, b.x, -(a.y * b.y)),
                       __builtin_fmaf(a.x, b.y,  a.y * b.x));
}

// radix-8 DIT butterfly on 8 points spaced h apart (3 stages in registers).
// wA = tw[j<<(12-st)], wB = tw[j<<(11-st)], wC = tw[j<<(10-st)].
__device__ inline void radix8(float2& u0, float2& u1, float2& u2, float2& u3,
                              float2& u4, float2& u5, float2& u6, float2& u7,
                              float2 wA, float2 wB, float2 wC) {
    float2 t1 = cmulf(wA, u1), t3 = cmulf(wA, u3), t5 = cmulf(wA, u5), t7 = cmulf(wA, u7);
    float2 a0 = f2add(u0, t1), a1 = f2sub(u0, t1);
    float2 a2 = f2add(u2, t3), a3 = f2sub(u2, t3);
    float2 a4 = f2add(u4, t5), a5 = f2sub(u4, t5);
    float2 a6 = f2add(u6, t7), a7 = f2sub(u6, t7);
    float2 s2 = cmulf(wB, a2), s3 = cmulf(wB, a3);
    float2 s6 = cmulf(wB, a6), s7 = cmulf(wB, a7);
    float2 b0 = f2add(a0, s2), b2 = f2sub(a0, s2);
    float2 b1 = make_float2(a1.x + s3.y, a1.y - s3.x);   // a1 + (-i)s3
    float2 b3 = make_float2(a1.x - s3.y, a1.y + s3.x);   // a1 - (-i)s3
    float2 b4 = f2add(a4, s6), b6 = f2sub(a4, s6);
    float2 b5 = make_float2(a5.x + s7.y, a5.y - s7.x);
    float2 b7 = make_float2(a5.x - s7.y, a5.y + s7.x);
    const float2 C8 = make_float2(0.70710678118654752f, -0.70710678118654752f);  // e^{-i pi/4}
    float2 wC1 = cmulf(wC, C8);
    float2 r4 = cmulf(wC, b4);
    float2 r5 = cmulf(wC1, b5);
    float2 r6t = cmulf(wC, b6);  float2 r6 = make_float2(r6t.y, -r6t.x);   // -i * wC * b6
    float2 r7t = cmulf(wC1, b7); float2 r7 = make_float2(r7t.y, -r7t.x);   // e^{-3i pi/4} wC b7
    u0 = f2add(b0, r4); u4 = f2sub(b0, r4);
    u1 = f2add(b1, r5); u5 = f2sub(b1, r5);
    u2 = f2add(b2, r6); u6 = f2sub(b2, r6);
    u3 = f2add(b3, r7); u7 = f2sub(b3, r7);
}

// ---------------- table kernel: trig[k] = (cos, sin)(2*pi*k/4096), f64-accurate ----------------
__global__ void k_tables(float2* __restrict__ trig) {
    int k = blockIdx.x * blockDim.x + threadIdx.x;
    if (k < 4096) {
        double th = (6.283185307179586476925286766559 * (double)k) / 4096.0;
        trig[k] = make_float2((float)cos(th), (float)sin(th));
    }
}

// ---------------- transpose + bit-reversal: q[b,l,h,e] -> T[(b,h,eo)][p][j] (float2) -----------
// T[bi][p][j] = ( x_{e0}[rev12(j)], x_{e0+1}[rev12(j)] ), e0 = eo*8+2p, region = 128KB per bi.
// Block (b:16, h:8, c4:16): rows l = c4 + 16t (t=0..255). rev12(l) = rev4(c4)*256 + rev8(t):
// destination runs are contiguous 256-element blocks -> fully coalesced float4 stores.
__global__ __launch_bounds__(256) void k_xpose(const float* __restrict__ q,
                                               float2* __restrict__ T) {
    __shared__ float tile[256][65];  // padded (+1)

    const int tid = threadIdx.x;
    const int bi  = blockIdx.x;
    const int b   = bi >> 7;
    const int h   = (bi >> 4) & 7;
    const int c4  = bi & 15;

    const float* qb = q + ((size_t)b * 4096 * 512) + (size_t)h * 64;
    for (int f = tid; f < 4096; f += NTHREADS) {
        int t = f >> 4, e4 = f & 15;
        const float4 v = *(const float4*)(qb + (size_t)(c4 + 16 * t) * 512 + e4 * 4);
        tile[t][e4 * 4 + 0] = v.x;
        tile[t][e4 * 4 + 1] = v.y;
        tile[t][e4 * 4 + 2] = v.z;
        tile[t][e4 * 4 + 3] = v.w;
    }
    __syncthreads();

    const int wave = tid >> 6, lane = tid & 63;
    const int rl  = __brev(lane) >> 26;  // rev6(lane)
    const int r4c = __brev(c4) >> 28;    // rev4(c4)
    for (int cc = wave; cc < 32; cc += 4) {
        int eo = cc >> 2, p = cc & 3;
        int col0 = eo * 8 + 2 * p;
        float2* dst = T + ((size_t)((b * 8 + h) * 8 + eo)) * 16384 + (size_t)p * 4096
                        + (size_t)r4c * 256;
#pragma unroll
        for (int r = 0; r < 2; ++r) {
            int ta = 2 * rl + r;
            int tb = ta + 128;
            float4 o;
            o.x = tile[ta][col0]; o.y = tile[ta][col0 + 1];
            o.z = tile[tb][col0]; o.w = tile[tb][col0 + 1];
            *(float4*)(dst + 2 * (64 * r + lane)) = o;
        }
    }
}

// ---------------- FFT (4 x radix-8 passes) + spectrum store + score accumulation ----------------
// grid: 1024 blocks = bi = (b*8+h)*8+eo. Reads its T region IN-PLACE from Xout buffer:
// pair plane p = Xout[bi*16384 + p*4096 .. +4096) (float2), fully loaded before the spectrum
// for signals e0=2p,2p+1 overwrites the exact same 32KB region.
__global__ __launch_bounds__(256) void k_fft(const float2* __restrict__ trig,
                                             float2* __restrict__ Xout,
                                             unsigned long long* __restrict__ score) {
    __shared__ float2 z[4096];     // 32 KB
    __shared__ float2 tw[2048];    // 16 KB  e^{-2pi i k/4096}
    __shared__ float  eacc[2048];  // 8 KB

    const int tid = threadIdx.x;
    const int bi  = blockIdx.x;

    for (int k = tid; k < 2048; k += NTHREADS) {
        float2 t = trig[k];
        tw[k] = make_float2(t.x, -t.y);
        eacc[k] = 0.f;
    }
    __syncthreads();

    const float2 ONE = make_float2(1.0f, 0.0f);

    for (int p = 0; p < 4; ++p) {
        const float2* plane = Xout + (size_t)bi * 16384 + (size_t)p * 4096;

        // pass 0 (stages 1-3, h=1, all twiddles unit -> constant-folded):
        for (int t = tid; t < 512; t += NTHREADS) {
            const float4 v01 = *(const float4*)(plane + 8 * t);
            const float4 v23 = *(const float4*)(plane + 8 * t + 2);
            const float4 v45 = *(const float4*)(plane + 8 * t + 4);
            const float4 v67 = *(const float4*)(plane + 8 * t + 6);
            float2 u0 = make_float2(v01.x, v01.y), u1 = make_float2(v01.z, v01.w);
            float2 u2 = make_float2(v23.x, v23.y), u3 = make_float2(v23.z, v23.w);
            float2 u4 = make_float2(v45.x, v45.y), u5 = make_float2(v45.z, v45.w);
            float2 u6 = make_float2(v67.x, v67.y), u7 = make_float2(v67.z, v67.w);
            radix8(u0, u1, u2, u3, u4, u5, u6, u7, ONE, ONE, ONE);
            z[8 * t + 0] = u0; z[8 * t + 1] = u1; z[8 * t + 2] = u2; z[8 * t + 3] = u3;
            z[8 * t + 4] = u4; z[8 * t + 5] = u5; z[8 * t + 6] = u6; z[8 * t + 7] = u7;
        }
        __syncthreads();

        // passes 1..3: stages (4,5,6), (7,8,9), (10,11,12); h = 8, 64, 512
#pragma unroll
        for (int p8 = 1; p8 <= 3; ++p8) {
            const int st = 1 + 3 * p8;
            const int h  = 1 << (st - 1);
            for (int t = tid; t < 512; t += NTHREADS) {
                const int j = t & (h - 1);
                const int g = t >> (st - 1);
                const int i0 = (g << (st + 2)) + j;
                float2 u0 = z[i0],         u1 = z[i0 + h],     u2 = z[i0 + 2 * h], u3 = z[i0 + 3 * h];
                float2 u4 = z[i0 + 4 * h], u5 = z[i0 + 5 * h], u6 = z[i0 + 6 * h], u7 = z[i0 + 7 * h];
                const float2 wA = tw[j << (12 - st)];
                const float2 wB = tw[j << (11 - st)];
                const float2 wC = tw[j << (10 - st)];
                radix8(u0, u1, u2, u3, u4, u5, u6, u7, wA, wB, wC);
                z[i0]         = u0; z[i0 + h]     = u1; z[i0 + 2 * h] = u2; z[i0 + 3 * h] = u3;
                z[i0 + 4 * h] = u4; z[i0 + 5 * h] = u5; z[i0 + 6 * h] = u6; z[i0 + 7 * h] = u7;
            }
            __syncthreads();
        }

        // unpack two real spectra; store (overwrites this pair's own plane); accumulate energy
        {
            const size_t s0 = (size_t)bi * 16384 + (size_t)p * 4096;  // = signal (bi*8+2p) * 2048
            for (int t = tid; t < 2048; t += NTHREADS) {
                int m = t + 1;
                float2 Za = z[m];
                float2 Zb = z[4096 - m];
                float Xr0 = 0.5f * (Za.x + Zb.x);
                float Xi0 = 0.5f * (Za.y - Zb.y);
                float Xr1 = 0.5f * (Za.y + Zb.y);
                float Xi1 = 0.5f * (Zb.x - Za.x);
                Xout[s0 + t]        = make_float2(Xr0, Xi0);
                Xout[s0 + 2048 + t] = make_float2(Xr1, Xi1);
                eacc[t] += Xr0 * Xr0 + Xi0 * Xi0 + Xr1 * Xr1 + Xi1 * Xi1;
            }
        }
        __syncthreads();  // protect z before next pair's load
    }

    // deterministic reduction: fixed-point u64 atomics (integer adds commute exactly)
    for (int t = tid; t < 2048; t += NTHREADS) {
        unsigned long long v = (unsigned long long)llrintf(eacc[t] * 1048576.0f);  // 2^20
        atomicAdd(&score[t], v);
    }
}

// ---------------- top-64, parallelized: 8 blocks x 256 threads, one candidate per thread -------
// rank-by-count, jax.lax.top_k tie semantics (desc, lower index first). Ranks are unique ->
// race-free scatter. Identical arithmetic to the serial version -> same deterministic result.
__global__ __launch_bounds__(256) void k_topk(const unsigned long long* __restrict__ score,
                                              int* __restrict__ idx) {
    __shared__ unsigned long long s[2048];
    const int tid = threadIdx.x;
    for (int t = tid; t < 2048; t += 256) s[t] = score[t];
    __syncthreads();

    const int t = blockIdx.x * 256 + tid;  // 0..2047
    const unsigned long long my = s[t];
    int rank = 0;
#pragma unroll 8
    for (int u = 0; u < 2048; ++u) {
        unsigned long long o = s[u];
        rank += (int)((o > my) || (o == my && u < t));
    }
    if (rank < 64) idx[rank] = t + 1;  // store frequency index m
}

// ---------------- gather + complex projection: Y[b,j,h,f] = sum_e X[b,idx_j,h,e] * W[j,h,e,f] ----
// grid: 512 blocks = (j:64, h:8). Y stored as [b][j][h*64+f] (hf fastest) for the synth GEMM.
__global__ __launch_bounds__(256) void k_proj(const float2* __restrict__ X,
                                              const float* __restrict__ wr,
                                              const float* __restrict__ wi,
                                              const int* __restrict__ idx,
                                              float2* __restrict__ Y) {
    __shared__ float2 xs[16 * 64];   // [b][e]  8 KB
    __shared__ float  wrs[64 * 64];  // [e][f] 16 KB
    __shared__ float  wis[64 * 64];  // 16 KB

    const int tid = threadIdx.x;
    const int j = blockIdx.x >> 3;
    const int h = blockIdx.x & 7;
    const int m = idx[j];

    for (int t = tid; t < 1024; t += NTHREADS) {
        int b = t >> 6, e = t & 63;
        xs[t] = X[((size_t)((b * 8 + h) * 64 + e)) * 2048 + (size_t)(m - 1)];
    }
    const float* wrb = wr + ((size_t)(j * 8 + h)) * 4096;
    const float* wib = wi + ((size_t)(j * 8 + h)) * 4096;
    for (int t = tid; t < 4096; t += NTHREADS) { wrs[t] = wrb[t]; wis[t] = wib[t]; }
    __syncthreads();

    const int b  = tid >> 4;   // 0..15
    const int fg = tid & 15;   // 0..15
    for (int fo = 0; fo < 4; ++fo) {
        int f = fg * 4 + fo;
        float yr = 0.f, yi = 0.f;
        for (int e = 0; e < 64; ++e) {
            float2 x = xs[b * 64 + e];
            float a = wrs[e * 64 + f], c = wis[e * 64 + f];
            yr = __builtin_fmaf(x.x, a, yr); yr = __builtin_fmaf(-x.y, c, yr);
            yi = __builtin_fmaf(x.x, c, yi); yi = __builtin_fmaf( x.y, a, yi);
        }
        Y[((size_t)b * 64 + j) * 512 + (size_t)(h * 64 + f)] = make_float2(yr, yi);
    }
}

// ---------------- synthesis as f32 GEMM: out[b,l,hf] = sum_j A[l,j] (.) Y[b,j,hf] -------------
// A[l,j] = e^{+i 2pi j l / 4096}, generated per-thread by complex rotators (no LDS lookups).
// grid: 2048 blocks = (b:16, hft:4, lt:32). Block tile: 128 l x 128 hf. Thread: 8l x 8hf.
__global__ __launch_bounds__(256) void k_synth(const float2* __restrict__ Y,
                                               const float2* __restrict__ trig,
                                               float* __restrict__ out) {
    __shared__ float2 ys[64][128];  // 64 KB, pre-scaled: j=0 -> (Yr/N, 0); j>0 -> (2/N)*Y

    const int tid = threadIdx.x;
    const int bi  = blockIdx.x;
    const int b   = bi >> 7;        // 16
    const int hft = (bi >> 5) & 3;  // 4
    const int lt  = bi & 31;        // 32

    const float invN = 1.0f / 4096.0f;
    const float2* yb = Y + (size_t)b * 64 * 512 + (size_t)hft * 128;
    for (int t = tid; t < 64 * 128; t += NTHREADS) {
        int j = t >> 7, cc = t & 127;
        float2 y = yb[(size_t)j * 512 + cc];
        if (j == 0) ys[0][cc] = make_float2(y.x * invN, 0.0f);
        else        ys[j][cc] = make_float2(y.x * (2.0f * invN), y.y * (2.0f * invN));
    }
    __syncthreads();

    const int r = tid >> 4;         // 0..15
    const int c = tid & 15;         // 0..15
    const int l0 = lt * 128 + r * 8;

    float2 rot[8], w[8];
#pragma unroll
    for (int v = 0; v < 8; ++v) {
        w[v] = trig[(l0 + v) & 4095];
        rot[v] = make_float2(1.0f, 0.0f);
    }

    float acc[8][8];
#pragma unroll
    for (int v = 0; v < 8; ++v)
#pragma unroll
        for (int u = 0; u < 8; ++u) acc[v][u] = 0.0f;

    for (int j = 0; j < 64; ++j) {
        float2 yv[8];
#pragma unroll
        for (int u = 0; u < 8; ++u) {
            yv[u] = ys[j][c * 2 + (u & 1) + (u >> 1) * 32];
        }
#pragma unroll
        for (int v = 0; v < 8; ++v) {
            const float cx = rot[v].x, sx = rot[v].y;
#pragma unroll
            for (int u = 0; u < 8; ++u) {
                float a = acc[v][u];
                a = __builtin_fmaf(cx, yv[u].x, a);       // two fused chains, 2 VALU/MAC
                a = __builtin_fmaf(-sx, yv[u].y, a);
                acc[v][u] = a;
            }
        }
#pragma unroll
        for (int v = 0; v < 8; ++v) {
            float nx = __builtin_fmaf(rot[v].x, w[v].x, -(rot[v].y * w[v].y));
            float ny = __builtin_fmaf(rot[v].x, w[v].y,  (rot[v].y * w[v].x));
            rot[v] = make_float2(nx, ny);
        }
    }

#pragma unroll
    for (int v = 0; v < 8; ++v) {
        float* ob = out + ((size_t)(b * 4096 + l0 + v)) * 512 + (size_t)hft * 128;
#pragma unroll
        for (int k = 0; k < 4; ++k) {
            float2 st = make_float2(acc[v][2 * k], acc[v][2 * k + 1]);
            *(float2*)(ob + k * 32 + c * 2) = st;
        }
    }
}

// ---------------- launch ----------------
extern "C" void kernel_launch(void* const* d_in, const int* in_sizes, int n_in,
                              void* d_out, int out_size, void* d_ws, size_t ws_size,
                              hipStream_t stream) {
    const float* q  = (const float*)d_in[0];
    const float* wr = (const float*)d_in[3];
    const float* wi = (const float*)d_in[4];

    char* ws = (char*)d_ws;
    float2*             trig  = (float2*)(ws + 0);                  // 32 KB
    unsigned long long* score = (unsigned long long*)(ws + 32768);  // 16 KB
    int*                idx   = (int*)(ws + 49152);                 // 256 B
    float2*             Y     = (float2*)(ws + 65536);              // 4 MB

    // d_out triples as: transposed-q scratch T -> spectrum Xout (in-place) -> final output.
    float2* Xs = (float2*)d_out;

    hipMemsetAsync(score, 0, 2048 * sizeof(unsigned long long), stream);
    k_tables<<<16, 256, 0, stream>>>(trig);
    k_xpose<<<2048, 256, 0, stream>>>(q, Xs);          // (b:16, h:8, c4:16)
    k_fft<<<1024, 256, 0, stream>>>(trig, Xs, score);  // in-place T -> spectra
    k_topk<<<8, 256, 0, stream>>>(score, idx);         // 2048 candidates, 1/thread
    k_proj<<<512, 256, 0, stream>>>(Xs, wr, wi, idx, Y);
    k_synth<<<2048, 256, 0, stream>>>(Y, trig, (float*)d_out);  // (b:16, hft:4, lt:32)
}

// Round 7
// 300.159 us; speedup vs baseline: 3.3563x; 1.1609x over previous
//
#include <hip/hip_runtime.h>

// Problem constants: B=16, L=4096, H=8, E=64, K=64, F=2049 (rfft bins)
// Only bins m in [1,2048] matter (bin 0 excluded from top-k; out_ft uses slots 0..63).

#define NTHREADS 256

__device__ inline float2 f2add(float2 a, float2 b) { return make_float2(a.x + b.x, a.y + b.y); }
__device__ inline float2 f2sub(float2 a, float2 b) { return make_float2(a.x - b.x, a.y - b.y); }
// complex mul, exactly 4 VALU (mul, fma, mul, fma)
__device__ inline float2 cmulf(float2 a, float2 b) {
    return make_float2(__builtin_fmaf(a.x, b.x, -(a.y * b.y)),
                       __builtin_fmaf(a.x, b.y,  a.y * b.x));
}

// radix-8 DIT butterfly on 8 points spaced h apart (3 stages in registers).
// wA = tw[j<<(12-st)], wB = tw[j<<(11-st)], wC = tw[j<<(10-st)].
__device__ inline void radix8(float2& u0, float2& u1, float2& u2, float2& u3,
                              float2& u4, float2& u5, float2& u6, float2& u7,
                              float2 wA, float2 wB, float2 wC) {
    float2 t1 = cmulf(wA, u1), t3 = cmulf(wA, u3), t5 = cmulf(wA, u5), t7 = cmulf(wA, u7);
    float2 a0 = f2add(u0, t1), a1 = f2sub(u0, t1);
    float2 a2 = f2add(u2, t3), a3 = f2sub(u2, t3);
    float2 a4 = f2add(u4, t5), a5 = f2sub(u4, t5);
    float2 a6 = f2add(u6, t7), a7 = f2sub(u6, t7);
    float2 s2 = cmulf(wB, a2), s3 = cmulf(wB, a3);
    float2 s6 = cmulf(wB, a6), s7 = cmulf(wB, a7);
    float2 b0 = f2add(a0, s2), b2 = f2sub(a0, s2);
    float2 b1 = make_float2(a1.x + s3.y, a1.y - s3.x);   // a1 + (-i)s3
    float2 b3 = make_float2(a1.x - s3.y, a1.y + s3.x);   // a1 - (-i)s3
    float2 b4 = f2add(a4, s6), b6 = f2sub(a4, s6);
    float2 b5 = make_float2(a5.x + s7.y, a5.y - s7.x);
    float2 b7 = make_float2(a5.x - s7.y, a5.y + s7.x);
    const float2 C8 = make_float2(0.70710678118654752f, -0.70710678118654752f);  // e^{-i pi/4}
    float2 wC1 = cmulf(wC, C8);
    float2 r4 = cmulf(wC, b4);
    float2 r5 = cmulf(wC1, b5);
    float2 r6t = cmulf(wC, b6);  float2 r6 = make_float2(r6t.y, -r6t.x);   // -i * wC * b6
    float2 r7t = cmulf(wC1, b7); float2 r7 = make_float2(r7t.y, -r7t.x);   // e^{-3i pi/4} wC b7
    u0 = f2add(b0, r4); u4 = f2sub(b0, r4);
    u1 = f2add(b1, r5); u5 = f2sub(b1, r5);
    u2 = f2add(b2, r6); u6 = f2sub(b2, r6);
    u3 = f2add(b3, r7); u7 = f2sub(b3, r7);
}

// ---------------- table kernel: trig[k] = (cos, sin)(2*pi*k/4096), f64-accurate ----------------
__global__ void k_tables(float2* __restrict__ trig) {
    int k = blockIdx.x * blockDim.x + threadIdx.x;
    if (k < 4096) {
        double th = (6.283185307179586476925286766559 * (double)k) / 4096.0;
        trig[k] = make_float2((float)cos(th), (float)sin(th));
    }
}

// ---------------- transpose + bit-reversal: q[b,l,h,e] -> T[(b,h,eo)][p][j] (float2) -----------
// T[bi][p][j] = ( x_{e0}[rev12(j)], x_{e0+1}[rev12(j)] ), e0 = eo*8+2p, region = 128KB per bi.
// Block (b:16, h:8, c4:16): rows l = c4 + 16t (t=0..255). rev12(l) = rev4(c4)*256 + rev8(t):
// destination runs are contiguous 256-element blocks -> fully coalesced float4 stores.
__global__ __launch_bounds__(256) void k_xpose(const float* __restrict__ q,
                                               float2* __restrict__ T) {
    __shared__ float tile[256][65];  // padded (+1)

    const int tid = threadIdx.x;
    const int bi  = blockIdx.x;
    const int b   = bi >> 7;
    const int h   = (bi >> 4) & 7;
    const int c4  = bi & 15;

    const float* qb = q + ((size_t)b * 4096 * 512) + (size_t)h * 64;
    for (int f = tid; f < 4096; f += NTHREADS) {
        int t = f >> 4, e4 = f & 15;
        const float4 v = *(const float4*)(qb + (size_t)(c4 + 16 * t) * 512 + e4 * 4);
        tile[t][e4 * 4 + 0] = v.x;
        tile[t][e4 * 4 + 1] = v.y;
        tile[t][e4 * 4 + 2] = v.z;
        tile[t][e4 * 4 + 3] = v.w;
    }
    __syncthreads();

    const int wave = tid >> 6, lane = tid & 63;
    const int rl  = __brev(lane) >> 26;  // rev6(lane)
    const int r4c = __brev(c4) >> 28;    // rev4(c4)
    for (int cc = wave; cc < 32; cc += 4) {
        int eo = cc >> 2, p = cc & 3;
        int col0 = eo * 8 + 2 * p;
        float2* dst = T + ((size_t)((b * 8 + h) * 8 + eo)) * 16384 + (size_t)p * 4096
                        + (size_t)r4c * 256;
#pragma unroll
        for (int r = 0; r < 2; ++r) {
            int ta = 2 * rl + r;
            int tb = ta + 128;
            float4 o;
            o.x = tile[ta][col0]; o.y = tile[ta][col0 + 1];
            o.z = tile[tb][col0]; o.w = tile[tb][col0 + 1];
            *(float4*)(dst + 2 * (64 * r + lane)) = o;
        }
    }
}

// ---------------- FFT (4 x radix-8 passes) + spectrum store + score accumulation ----------------
// grid: 1024 blocks = bi = (b*8+h)*8+eo. Reads its T region IN-PLACE from Xout buffer:
// pair plane p = Xout[bi*16384 + p*4096 .. +4096) (float2), fully loaded before the spectrum
// for signals e0=2p,2p+1 overwrites the exact same 32KB region.
__global__ __launch_bounds__(256) void k_fft(const float2* __restrict__ trig,
                                             float2* __restrict__ Xout,
                                             unsigned long long* __restrict__ score) {
    __shared__ float2 z[4096];     // 32 KB
    __shared__ float2 tw[2048];    // 16 KB  e^{-2pi i k/4096}
    __shared__ float  eacc[2048];  // 8 KB

    const int tid = threadIdx.x;
    const int bi  = blockIdx.x;

    for (int k = tid; k < 2048; k += NTHREADS) {
        float2 t = trig[k];
        tw[k] = make_float2(t.x, -t.y);
        eacc[k] = 0.f;
    }
    __syncthreads();

    const float2 ONE = make_float2(1.0f, 0.0f);

    for (int p = 0; p < 4; ++p) {
        const float2* plane = Xout + (size_t)bi * 16384 + (size_t)p * 4096;

        // pass 0 (stages 1-3, h=1, all twiddles unit -> constant-folded):
        for (int t = tid; t < 512; t += NTHREADS) {
            const float4 v01 = *(const float4*)(plane + 8 * t);
            const float4 v23 = *(const float4*)(plane + 8 * t + 2);
            const float4 v45 = *(const float4*)(plane + 8 * t + 4);
            const float4 v67 = *(const float4*)(plane + 8 * t + 6);
            float2 u0 = make_float2(v01.x, v01.y), u1 = make_float2(v01.z, v01.w);
            float2 u2 = make_float2(v23.x, v23.y), u3 = make_float2(v23.z, v23.w);
            float2 u4 = make_float2(v45.x, v45.y), u5 = make_float2(v45.z, v45.w);
            float2 u6 = make_float2(v67.x, v67.y), u7 = make_float2(v67.z, v67.w);
            radix8(u0, u1, u2, u3, u4, u5, u6, u7, ONE, ONE, ONE);
            z[8 * t + 0] = u0; z[8 * t + 1] = u1; z[8 * t + 2] = u2; z[8 * t + 3] = u3;
            z[8 * t + 4] = u4; z[8 * t + 5] = u5; z[8 * t + 6] = u6; z[8 * t + 7] = u7;
        }
        __syncthreads();

        // passes 1..3: stages (4,5,6), (7,8,9), (10,11,12); h = 8, 64, 512
#pragma unroll
        for (int p8 = 1; p8 <= 3; ++p8) {
            const int st = 1 + 3 * p8;
            const int h  = 1 << (st - 1);
            for (int t = tid; t < 512; t += NTHREADS) {
                const int j = t & (h - 1);
                const int g = t >> (st - 1);
                const int i0 = (g << (st + 2)) + j;
                float2 u0 = z[i0],         u1 = z[i0 + h],     u2 = z[i0 + 2 * h], u3 = z[i0 + 3 * h];
                float2 u4 = z[i0 + 4 * h], u5 = z[i0 + 5 * h], u6 = z[i0 + 6 * h], u7 = z[i0 + 7 * h];
                const float2 wA = tw[j << (12 - st)];
                const float2 wB = tw[j << (11 - st)];
                const float2 wC = tw[j << (10 - st)];
                radix8(u0, u1, u2, u3, u4, u5, u6, u7, wA, wB, wC);
                z[i0]         = u0; z[i0 + h]     = u1; z[i0 + 2 * h] = u2; z[i0 + 3 * h] = u3;
                z[i0 + 4 * h] = u4; z[i0 + 5 * h] = u5; z[i0 + 6 * h] = u6; z[i0 + 7 * h] = u7;
            }
            __syncthreads();
        }

        // unpack two real spectra; store (overwrites this pair's own plane); accumulate energy
        {
            const size_t s0 = (size_t)bi * 16384 + (size_t)p * 4096;  // = signal (bi*8+2p) * 2048
            for (int t = tid; t < 2048; t += NTHREADS) {
                int m = t + 1;
                float2 Za = z[m];
                float2 Zb = z[4096 - m];
                float Xr0 = 0.5f * (Za.x + Zb.x);
                float Xi0 = 0.5f * (Za.y - Zb.y);
                float Xr1 = 0.5f * (Za.y + Zb.y);
                float Xi1 = 0.5f * (Zb.x - Za.x);
                Xout[s0 + t]        = make_float2(Xr0, Xi0);
                Xout[s0 + 2048 + t] = make_float2(Xr1, Xi1);
                eacc[t] += Xr0 * Xr0 + Xi0 * Xi0 + Xr1 * Xr1 + Xi1 * Xi1;
            }
        }
        __syncthreads();  // protect z before next pair's load
    }

    // deterministic reduction: fixed-point u64 atomics (integer adds commute exactly)
    for (int t = tid; t < 2048; t += NTHREADS) {
        unsigned long long v = (unsigned long long)llrintf(eacc[t] * 1048576.0f);  // 2^20
        atomicAdd(&score[t], v);
    }
}

// ---------------- top-64, parallelized: 8 blocks x 256 threads, one candidate per thread -------
// rank-by-count, jax.lax.top_k tie semantics (desc, lower index first). Ranks are unique ->
// race-free scatter. Identical arithmetic to the serial version -> same deterministic result.
__global__ __launch_bounds__(256) void k_topk(const unsigned long long* __restrict__ score,
                                              int* __restrict__ idx) {
    __shared__ unsigned long long s[2048];
    const int tid = threadIdx.x;
    for (int t = tid; t < 2048; t += 256) s[t] = score[t];
    __syncthreads();

    const int t = blockIdx.x * 256 + tid;  // 0..2047
    const unsigned long long my = s[t];
    int rank = 0;
#pragma unroll 8
    for (int u = 0; u < 2048; ++u) {
        unsigned long long o = s[u];
        rank += (int)((o > my) || (o == my && u < t));
    }
    if (rank < 64) idx[rank] = t + 1;  // store frequency index m
}

// ---------------- gather + complex projection: Y[b,j,h,f] = sum_e X[b,idx_j,h,e] * W[j,h,e,f] ----
// grid: 512 blocks = (j:64, h:8). Y stored as [b][j][h*64+f] (hf fastest) for the synth GEMM.
__global__ __launch_bounds__(256) void k_proj(const float2* __restrict__ X,
                                              const float* __restrict__ wr,
                                              const float* __restrict__ wi,
                                              const int* __restrict__ idx,
                                              float2* __restrict__ Y) {
    __shared__ float2 xs[16 * 64];   // [b][e]  8 KB
    __shared__ float  wrs[64 * 64];  // [e][f] 16 KB
    __shared__ float  wis[64 * 64];  // 16 KB

    const int tid = threadIdx.x;
    const int j = blockIdx.x >> 3;
    const int h = blockIdx.x & 7;
    const int m = idx[j];

    for (int t = tid; t < 1024; t += NTHREADS) {
        int b = t >> 6, e = t & 63;
        xs[t] = X[((size_t)((b * 8 + h) * 64 + e)) * 2048 + (size_t)(m - 1)];
    }
    const float* wrb = wr + ((size_t)(j * 8 + h)) * 4096;
    const float* wib = wi + ((size_t)(j * 8 + h)) * 4096;
    for (int t = tid; t < 4096; t += NTHREADS) { wrs[t] = wrb[t]; wis[t] = wib[t]; }
    __syncthreads();

    const int b  = tid >> 4;   // 0..15
    const int fg = tid & 15;   // 0..15
    for (int fo = 0; fo < 4; ++fo) {
        int f = fg * 4 + fo;
        float yr = 0.f, yi = 0.f;
        for (int e = 0; e < 64; ++e) {
            float2 x = xs[b * 64 + e];
            float a = wrs[e * 64 + f], c = wis[e * 64 + f];
            yr = __builtin_fmaf(x.x, a, yr); yr = __builtin_fmaf(-x.y, c, yr);
            yi = __builtin_fmaf(x.x, c, yi); yi = __builtin_fmaf( x.y, a, yi);
        }
        Y[((size_t)b * 64 + j) * 512 + (size_t)(h * 64 + f)] = make_float2(yr, yi);
    }
}

// ---------------- synthesis as f32 GEMM with half-wave symmetry --------------------------------
// out(l)      = Re sum_j Yt_j w^{jl} = ae + ao   (ae: even j, ao: odd j, real chains only)
// out(l+2048) =                        ae - ao   (w^{j(l+2048)} = w^{jl} (-1)^j)
// grid: 1024 blocks = (b:16, hft:4, lt:16). Block: base-l tile 128 (rows l and l+2048) x 128 hf.
// Thread: 8 base-l x 8 hf, acc_e/acc_o pairs; rotators advance per j as before.
__global__ __launch_bounds__(256, 2) void k_synth(const float2* __restrict__ Y,
                                                  const float2* __restrict__ trig,
                                                  float* __restrict__ out) {
    __shared__ float2 ys[64][128];  // 64 KB, pre-scaled: j=0 -> (Yr/N, 0); j>0 -> (2/N)*Y

    const int tid = threadIdx.x;
    const int bi  = blockIdx.x;
    const int b   = bi >> 6;        // 16
    const int hft = (bi >> 4) & 3;  // 4
    const int lt  = bi & 15;        // 16

    const float invN = 1.0f / 4096.0f;
    const float2* yb = Y + (size_t)b * 64 * 512 + (size_t)hft * 128;
    for (int t = tid; t < 64 * 128; t += NTHREADS) {
        int j = t >> 7, cc = t & 127;
        float2 y = yb[(size_t)j * 512 + cc];
        if (j == 0) ys[0][cc] = make_float2(y.x * invN, 0.0f);
        else        ys[j][cc] = make_float2(y.x * (2.0f * invN), y.y * (2.0f * invN));
    }
    __syncthreads();

    const int r = tid >> 4;         // 0..15
    const int c = tid & 15;         // 0..15
    const int l0 = lt * 128 + r * 8;  // base-l in [0, 2048)

    float2 rot[8], w[8];
#pragma unroll
    for (int v = 0; v < 8; ++v) {
        w[v] = trig[(l0 + v) & 4095];
        rot[v] = make_float2(1.0f, 0.0f);
    }

    float ae[8][8], ao[8][8];
#pragma unroll
    for (int v = 0; v < 8; ++v)
#pragma unroll
        for (int u = 0; u < 8; ++u) { ae[v][u] = 0.0f; ao[v][u] = 0.0f; }

    for (int j = 0; j < 64; j += 2) {
        // even j -> ae
        {
            float2 yv[8];
#pragma unroll
            for (int u = 0; u < 8; ++u) yv[u] = ys[j][c * 2 + (u & 1) + (u >> 1) * 32];
#pragma unroll
            for (int v = 0; v < 8; ++v) {
                const float cx = rot[v].x, sx = rot[v].y;
#pragma unroll
                for (int u = 0; u < 8; ++u) {
                    float a = ae[v][u];
                    a = __builtin_fmaf(cx, yv[u].x, a);
                    a = __builtin_fmaf(-sx, yv[u].y, a);
                    ae[v][u] = a;
                }
            }
#pragma unroll
            for (int v = 0; v < 8; ++v) {
                float nx = __builtin_fmaf(rot[v].x, w[v].x, -(rot[v].y * w[v].y));
                float ny = __builtin_fmaf(rot[v].x, w[v].y,  (rot[v].y * w[v].x));
                rot[v] = make_float2(nx, ny);
            }
        }
        // odd j+1 -> ao
        {
            float2 yv[8];
#pragma unroll
            for (int u = 0; u < 8; ++u) yv[u] = ys[j + 1][c * 2 + (u & 1) + (u >> 1) * 32];
#pragma unroll
            for (int v = 0; v < 8; ++v) {
                const float cx = rot[v].x, sx = rot[v].y;
#pragma unroll
                for (int u = 0; u < 8; ++u) {
                    float a = ao[v][u];
                    a = __builtin_fmaf(cx, yv[u].x, a);
                    a = __builtin_fmaf(-sx, yv[u].y, a);
                    ao[v][u] = a;
                }
            }
#pragma unroll
            for (int v = 0; v < 8; ++v) {
                float nx = __builtin_fmaf(rot[v].x, w[v].x, -(rot[v].y * w[v].y));
                float ny = __builtin_fmaf(rot[v].x, w[v].y,  (rot[v].y * w[v].x));
                rot[v] = make_float2(nx, ny);
            }
        }
    }

    // stores: row l0+v gets ae+ao; row l0+v+2048 gets ae-ao
#pragma unroll
    for (int v = 0; v < 8; ++v) {
        float* ob0 = out + ((size_t)(b * 4096 + l0 + v)) * 512 + (size_t)hft * 128;
        float* ob1 = ob0 + (size_t)2048 * 512;
#pragma unroll
        for (int k = 0; k < 4; ++k) {
            float2 s0 = make_float2(ae[v][2 * k] + ao[v][2 * k],
                                    ae[v][2 * k + 1] + ao[v][2 * k + 1]);
            float2 s1 = make_float2(ae[v][2 * k] - ao[v][2 * k],
                                    ae[v][2 * k + 1] - ao[v][2 * k + 1]);
            *(float2*)(ob0 + k * 32 + c * 2) = s0;
            *(float2*)(ob1 + k * 32 + c * 2) = s1;
        }
    }
}

// ---------------- launch ----------------
extern "C" void kernel_launch(void* const* d_in, const int* in_sizes, int n_in,
                              void* d_out, int out_size, void* d_ws, size_t ws_size,
                              hipStream_t stream) {
    const float* q  = (const float*)d_in[0];
    const float* wr = (const float*)d_in[3];
    const float* wi = (const float*)d_in[4];

    char* ws = (char*)d_ws;
    float2*             trig  = (float2*)(ws + 0);                  // 32 KB
    unsigned long long* score = (unsigned long long*)(ws + 32768);  // 16 KB
    int*                idx   = (int*)(ws + 49152);                 // 256 B
    float2*             Y     = (float2*)(ws + 65536);              // 4 MB

    // d_out triples as: transposed-q scratch T -> spectrum Xout (in-place) -> final output.
    float2* Xs = (float2*)d_out;

    hipMemsetAsync(score, 0, 2048 * sizeof(unsigned long long), stream);
    k_tables<<<16, 256, 0, stream>>>(trig);
    k_xpose<<<2048, 256, 0, stream>>>(q, Xs);          // (b:16, h:8, c4:16)
    k_fft<<<1024, 256, 0, stream>>>(trig, Xs, score);  // in-place T -> spectra
    k_topk<<<8, 256, 0, stream>>>(score, idx);         // 2048 candidates, 1/thread
    k_proj<<<512, 256, 0, stream>>>(Xs, wr, wi, idx, Y);
    k_synth<<<1024, 256, 0, stream>>>(Y, trig, (float*)d_out);  // (b:16, hft:4, lt:16)
}

// Round 8
// 280.279 us; speedup vs baseline: 3.5944x; 1.0709x over previous
//
#include <hip/hip_runtime.h>

// Problem constants: B=16, L=4096, H=8, E=64, K=64, F=2049 (rfft bins)
// Only bins m in [1,2048] matter (bin 0 excluded from top-k; out_ft uses slots 0..63).

#define NTHREADS 256

__device__ inline float2 f2add(float2 a, float2 b) { return make_float2(a.x + b.x, a.y + b.y); }
__device__ inline float2 f2sub(float2 a, float2 b) { return make_float2(a.x - b.x, a.y - b.y); }
// complex mul, exactly 4 VALU (mul, fma, mul, fma)
__device__ inline float2 cmulf(float2 a, float2 b) {
    return make_float2(__builtin_fmaf(a.x, b.x, -(a.y * b.y)),
                       __builtin_fmaf(a.x, b.y,  a.y * b.x));
}

// radix-8 DIT butterfly on 8 points spaced h apart (3 stages in registers).
__device__ inline void radix8(float2& u0, float2& u1, float2& u2, float2& u3,
                              float2& u4, float2& u5, float2& u6, float2& u7,
                              float2 wA, float2 wB, float2 wC) {
    float2 t1 = cmulf(wA, u1), t3 = cmulf(wA, u3), t5 = cmulf(wA, u5), t7 = cmulf(wA, u7);
    float2 a0 = f2add(u0, t1), a1 = f2sub(u0, t1);
    float2 a2 = f2add(u2, t3), a3 = f2sub(u2, t3);
    float2 a4 = f2add(u4, t5), a5 = f2sub(u4, t5);
    float2 a6 = f2add(u6, t7), a7 = f2sub(u6, t7);
    float2 s2 = cmulf(wB, a2), s3 = cmulf(wB, a3);
    float2 s6 = cmulf(wB, a6), s7 = cmulf(wB, a7);
    float2 b0 = f2add(a0, s2), b2 = f2sub(a0, s2);
    float2 b1 = make_float2(a1.x + s3.y, a1.y - s3.x);   // a1 + (-i)s3
    float2 b3 = make_float2(a1.x - s3.y, a1.y + s3.x);   // a1 - (-i)s3
    float2 b4 = f2add(a4, s6), b6 = f2sub(a4, s6);
    float2 b5 = make_float2(a5.x + s7.y, a5.y - s7.x);
    float2 b7 = make_float2(a5.x - s7.y, a5.y + s7.x);
    const float2 C8 = make_float2(0.70710678118654752f, -0.70710678118654752f);  // e^{-i pi/4}
    float2 wC1 = cmulf(wC, C8);
    float2 r4 = cmulf(wC, b4);
    float2 r5 = cmulf(wC1, b5);
    float2 r6t = cmulf(wC, b6);  float2 r6 = make_float2(r6t.y, -r6t.x);   // -i * wC * b6
    float2 r7t = cmulf(wC1, b7); float2 r7 = make_float2(r7t.y, -r7t.x);   // e^{-3i pi/4} wC b7
    u0 = f2add(b0, r4); u4 = f2sub(b0, r4);
    u1 = f2add(b1, r5); u5 = f2sub(b1, r5);
    u2 = f2add(b2, r6); u6 = f2sub(b2, r6);
    u3 = f2add(b3, r7); u7 = f2sub(b3, r7);
}

// ---------------- table kernel: trig[k] = (cos, sin)(2*pi*k/4096), f64-accurate ----------------
__global__ void k_tables(float2* __restrict__ trig) {
    int k = blockIdx.x * blockDim.x + threadIdx.x;
    if (k < 4096) {
        double th = (6.283185307179586476925286766559 * (double)k) / 4096.0;
        trig[k] = make_float2((float)cos(th), (float)sin(th));
    }
}

// ---------------- transpose + bit-reversal: q[b,l,h,e] -> T[(b,h,eo)][p][j] (float2) -----------
__global__ __launch_bounds__(256) void k_xpose(const float* __restrict__ q,
                                               float2* __restrict__ T) {
    __shared__ float tile[256][65];  // padded (+1)

    const int tid = threadIdx.x;
    const int bi  = blockIdx.x;
    const int b   = bi >> 7;
    const int h   = (bi >> 4) & 7;
    const int c4  = bi & 15;

    const float* qb = q + ((size_t)b * 4096 * 512) + (size_t)h * 64;
    for (int f = tid; f < 4096; f += NTHREADS) {
        int t = f >> 4, e4 = f & 15;
        const float4 v = *(const float4*)(qb + (size_t)(c4 + 16 * t) * 512 + e4 * 4);
        tile[t][e4 * 4 + 0] = v.x;
        tile[t][e4 * 4 + 1] = v.y;
        tile[t][e4 * 4 + 2] = v.z;
        tile[t][e4 * 4 + 3] = v.w;
    }
    __syncthreads();

    const int wave = tid >> 6, lane = tid & 63;
    const int rl  = __brev(lane) >> 26;  // rev6(lane)
    const int r4c = __brev(c4) >> 28;    // rev4(c4)
    for (int cc = wave; cc < 32; cc += 4) {
        int eo = cc >> 2, p = cc & 3;
        int col0 = eo * 8 + 2 * p;
        float2* dst = T + ((size_t)((b * 8 + h) * 8 + eo)) * 16384 + (size_t)p * 4096
                        + (size_t)r4c * 256;
#pragma unroll
        for (int r = 0; r < 2; ++r) {
            int ta = 2 * rl + r;
            int tb = ta + 128;
            float4 o;
            o.x = tile[ta][col0]; o.y = tile[ta][col0 + 1];
            o.z = tile[tb][col0]; o.w = tile[tb][col0 + 1];
            *(float4*)(dst + 2 * (64 * r + lane)) = o;
        }
    }
}

// ---------------- FFT (4 x radix-8 passes) + spectrum store + score accumulation ----------------
__global__ __launch_bounds__(256) void k_fft(const float2* __restrict__ trig,
                                             float2* __restrict__ Xout,
                                             unsigned long long* __restrict__ score) {
    __shared__ float2 z[4096];     // 32 KB
    __shared__ float2 tw[2048];    // 16 KB  e^{-2pi i k/4096}
    __shared__ float  eacc[2048];  // 8 KB

    const int tid = threadIdx.x;
    const int bi  = blockIdx.x;

    for (int k = tid; k < 2048; k += NTHREADS) {
        float2 t = trig[k];
        tw[k] = make_float2(t.x, -t.y);
        eacc[k] = 0.f;
    }
    __syncthreads();

    const float2 ONE = make_float2(1.0f, 0.0f);

    for (int p = 0; p < 4; ++p) {
        const float2* plane = Xout + (size_t)bi * 16384 + (size_t)p * 4096;

        // pass 0 (stages 1-3, h=1, all twiddles unit -> constant-folded):
        for (int t = tid; t < 512; t += NTHREADS) {
            const float4 v01 = *(const float4*)(plane + 8 * t);
            const float4 v23 = *(const float4*)(plane + 8 * t + 2);
            const float4 v45 = *(const float4*)(plane + 8 * t + 4);
            const float4 v67 = *(const float4*)(plane + 8 * t + 6);
            float2 u0 = make_float2(v01.x, v01.y), u1 = make_float2(v01.z, v01.w);
            float2 u2 = make_float2(v23.x, v23.y), u3 = make_float2(v23.z, v23.w);
            float2 u4 = make_float2(v45.x, v45.y), u5 = make_float2(v45.z, v45.w);
            float2 u6 = make_float2(v67.x, v67.y), u7 = make_float2(v67.z, v67.w);
            radix8(u0, u1, u2, u3, u4, u5, u6, u7, ONE, ONE, ONE);
            z[8 * t + 0] = u0; z[8 * t + 1] = u1; z[8 * t + 2] = u2; z[8 * t + 3] = u3;
            z[8 * t + 4] = u4; z[8 * t + 5] = u5; z[8 * t + 6] = u6; z[8 * t + 7] = u7;
        }
        __syncthreads();

        // passes 1..3: stages (4,5,6), (7,8,9), (10,11,12); h = 8, 64, 512
#pragma unroll
        for (int p8 = 1; p8 <= 3; ++p8) {
            const int st = 1 + 3 * p8;
            const int h  = 1 << (st - 1);
            for (int t = tid; t < 512; t += NTHREADS) {
                const int j = t & (h - 1);
                const int g = t >> (st - 1);
                const int i0 = (g << (st + 2)) + j;
                float2 u0 = z[i0],         u1 = z[i0 + h],     u2 = z[i0 + 2 * h], u3 = z[i0 + 3 * h];
                float2 u4 = z[i0 + 4 * h], u5 = z[i0 + 5 * h], u6 = z[i0 + 6 * h], u7 = z[i0 + 7 * h];
                const float2 wA = tw[j << (12 - st)];
                const float2 wB = tw[j << (11 - st)];
                const float2 wC = tw[j << (10 - st)];
                radix8(u0, u1, u2, u3, u4, u5, u6, u7, wA, wB, wC);
                z[i0]         = u0; z[i0 + h]     = u1; z[i0 + 2 * h] = u2; z[i0 + 3 * h] = u3;
                z[i0 + 4 * h] = u4; z[i0 + 5 * h] = u5; z[i0 + 6 * h] = u6; z[i0 + 7 * h] = u7;
            }
            __syncthreads();
        }

        // unpack two real spectra; store (overwrites this pair's own plane); accumulate energy
        {
            const size_t s0 = (size_t)bi * 16384 + (size_t)p * 4096;  // = signal (bi*8+2p) * 2048
            for (int t = tid; t < 2048; t += NTHREADS) {
                int m = t + 1;
                float2 Za = z[m];
                float2 Zb = z[4096 - m];
                float Xr0 = 0.5f * (Za.x + Zb.x);
                float Xi0 = 0.5f * (Za.y - Zb.y);
                float Xr1 = 0.5f * (Za.y + Zb.y);
                float Xi1 = 0.5f * (Zb.x - Za.x);
                Xout[s0 + t]        = make_float2(Xr0, Xi0);
                Xout[s0 + 2048 + t] = make_float2(Xr1, Xi1);
                eacc[t] += Xr0 * Xr0 + Xi0 * Xi0 + Xr1 * Xr1 + Xi1 * Xi1;
            }
        }
        __syncthreads();  // protect z before next pair's load
    }

    // deterministic reduction: fixed-point u64 atomics (integer adds commute exactly)
    for (int t = tid; t < 2048; t += NTHREADS) {
        unsigned long long v = (unsigned long long)llrintf(eacc[t] * 1048576.0f);  // 2^20
        atomicAdd(&score[t], v);
    }
}

// ---------------- top-64, parallelized: 8 blocks x 256 threads, one candidate per thread -------
__global__ __launch_bounds__(256) void k_topk(const unsigned long long* __restrict__ score,
                                              int* __restrict__ idx) {
    __shared__ unsigned long long s[2048];
    const int tid = threadIdx.x;
    for (int t = tid; t < 2048; t += 256) s[t] = score[t];
    __syncthreads();

    const int t = blockIdx.x * 256 + tid;  // 0..2047
    const unsigned long long my = s[t];
    int rank = 0;
#pragma unroll 8
    for (int u = 0; u < 2048; ++u) {
        unsigned long long o = s[u];
        rank += (int)((o > my) || (o == my && u < t));
    }
    if (rank < 64) idx[rank] = t + 1;  // store frequency index m
}

// ---------------- gather + complex projection: Y[b,j,h,f] = sum_e X[b,idx_j,h,e] * W[j,h,e,f] ----
__global__ __launch_bounds__(256) void k_proj(const float2* __restrict__ X,
                                              const float* __restrict__ wr,
                                              const float* __restrict__ wi,
                                              const int* __restrict__ idx,
                                              float2* __restrict__ Y) {
    __shared__ float2 xs[16 * 64];   // [b][e]  8 KB
    __shared__ float  wrs[64 * 64];  // [e][f] 16 KB
    __shared__ float  wis[64 * 64];  // 16 KB

    const int tid = threadIdx.x;
    const int j = blockIdx.x >> 3;
    const int h = blockIdx.x & 7;
    const int m = idx[j];

    for (int t = tid; t < 1024; t += NTHREADS) {
        int b = t >> 6, e = t & 63;
        xs[t] = X[((size_t)((b * 8 + h) * 64 + e)) * 2048 + (size_t)(m - 1)];
    }
    const float* wrb = wr + ((size_t)(j * 8 + h)) * 4096;
    const float* wib = wi + ((size_t)(j * 8 + h)) * 4096;
    for (int t = tid; t < 4096; t += NTHREADS) { wrs[t] = wrb[t]; wis[t] = wib[t]; }
    __syncthreads();

    const int b  = tid >> 4;   // 0..15
    const int fg = tid & 15;   // 0..15
    for (int fo = 0; fo < 4; ++fo) {
        int f = fg * 4 + fo;
        float yr = 0.f, yi = 0.f;
        for (int e = 0; e < 64; ++e) {
            float2 x = xs[b * 64 + e];
            float a = wrs[e * 64 + f], c = wis[e * 64 + f];
            yr = __builtin_fmaf(x.x, a, yr); yr = __builtin_fmaf(-x.y, c, yr);
            yi = __builtin_fmaf(x.x, c, yi); yi = __builtin_fmaf( x.y, a, yi);
        }
        Y[((size_t)b * 64 + j) * 512 + (size_t)(h * 64 + f)] = make_float2(yr, yi);
    }
}

// ---------------- synthesis with full w-symmetry: 1 rotator -> 4 output rows -------------------
// f_j = Re(rot_j y_j), h_j = Im(rot_j y_j). With F0/F1/F2/F3 = sum of f over j%4 classes and
// H1/H3 = sum of h over odd classes (i^j twiddle for l+1024 is a free sign/swap under j%4 unroll):
//   out(l)      = F0+F1+F2+F3          out(l+2048) = F0-F1+F2-F3
//   out(l+1024) = (F0-F2)-(H1-H3)      out(l+3072) = (F0-F2)+(H1-H3)
// grid: 2048 blocks = (b:16, hft:8, lt:16). Block: 64 base-l (in [0,1024)) x 64 hf.
// Thread: 2 base-l (v) x 8 hf (u); 6x2x8 = 96 accumulators; 2 rotators.
__global__ __launch_bounds__(256, 2) void k_synth(const float2* __restrict__ Y,
                                                  const float2* __restrict__ trig,
                                                  float* __restrict__ out) {
    __shared__ float2 ys[64][64];  // 32 KB, pre-scaled: j=0 -> (Yr/N, 0); j>0 -> (2/N)*Y

    const int tid = threadIdx.x;
    const int bi  = blockIdx.x;
    const int b   = bi >> 7;        // 16
    const int hft = (bi >> 4) & 7;  // 8
    const int lt  = bi & 15;        // 16

    const float invN = 1.0f / 4096.0f;
    const float2* yb = Y + (size_t)b * 64 * 512 + (size_t)hft * 64;
    for (int t = tid; t < 64 * 64; t += NTHREADS) {
        int j = t >> 6, cc = t & 63;
        float2 y = yb[(size_t)j * 512 + cc];
        if (j == 0) ys[0][cc] = make_float2(y.x * invN, 0.0f);
        else        ys[j][cc] = make_float2(y.x * (2.0f * invN), y.y * (2.0f * invN));
    }
    __syncthreads();

    const int r = tid >> 3;          // 0..31
    const int c = tid & 7;           // 0..7
    const int l0 = lt * 64 + r * 2;  // base l (v=0) in [0, 1024)

    float2 rot[2], w[2];
#pragma unroll
    for (int v = 0; v < 2; ++v) {
        w[v] = trig[(l0 + v) & 4095];
        rot[v] = make_float2(1.0f, 0.0f);
    }

    float F0[2][8], F1[2][8], F2[2][8], F3[2][8], H1[2][8], H3[2][8];
#pragma unroll
    for (int v = 0; v < 2; ++v)
#pragma unroll
        for (int u = 0; u < 8; ++u) {
            F0[v][u] = F1[v][u] = F2[v][u] = F3[v][u] = 0.0f;
            H1[v][u] = H3[v][u] = 0.0f;
        }

    for (int j = 0; j < 64; j += 4) {
        // j+0 (even) -> F0
        {
            float2 yv[8];
#pragma unroll
            for (int u = 0; u < 8; ++u) yv[u] = ys[j][c * 2 + (u & 1) + (u >> 1) * 16];
#pragma unroll
            for (int v = 0; v < 2; ++v) {
                const float cx = rot[v].x, sx = rot[v].y;
#pragma unroll
                for (int u = 0; u < 8; ++u) {
                    float a = F0[v][u];
                    a = __builtin_fmaf(cx, yv[u].x, a);
                    a = __builtin_fmaf(-sx, yv[u].y, a);
                    F0[v][u] = a;
                }
                float nx = __builtin_fmaf(rot[v].x, w[v].x, -(rot[v].y * w[v].y));
                float ny = __builtin_fmaf(rot[v].x, w[v].y,  (rot[v].y * w[v].x));
                rot[v] = make_float2(nx, ny);
            }
        }
        // j+1 (odd) -> F1, H1
        {
            float2 yv[8];
#pragma unroll
            for (int u = 0; u < 8; ++u) yv[u] = ys[j + 1][c * 2 + (u & 1) + (u >> 1) * 16];
#pragma unroll
            for (int v = 0; v < 2; ++v) {
                const float cx = rot[v].x, sx = rot[v].y;
#pragma unroll
                for (int u = 0; u < 8; ++u) {
                    float a = F1[v][u], g = H1[v][u];
                    a = __builtin_fmaf(cx, yv[u].x, a);
                    a = __builtin_fmaf(-sx, yv[u].y, a);
                    g = __builtin_fmaf(sx, yv[u].x, g);
                    g = __builtin_fmaf(cx, yv[u].y, g);
                    F1[v][u] = a; H1[v][u] = g;
                }
                float nx = __builtin_fmaf(rot[v].x, w[v].x, -(rot[v].y * w[v].y));
                float ny = __builtin_fmaf(rot[v].x, w[v].y,  (rot[v].y * w[v].x));
                rot[v] = make_float2(nx, ny);
            }
        }
        // j+2 (even) -> F2
        {
            float2 yv[8];
#pragma unroll
            for (int u = 0; u < 8; ++u) yv[u] = ys[j + 2][c * 2 + (u & 1) + (u >> 1) * 16];
#pragma unroll
            for (int v = 0; v < 2; ++v) {
                const float cx = rot[v].x, sx = rot[v].y;
#pragma unroll
                for (int u = 0; u < 8; ++u) {
                    float a = F2[v][u];
                    a = __builtin_fmaf(cx, yv[u].x, a);
                    a = __builtin_fmaf(-sx, yv[u].y, a);
                    F2[v][u] = a;
                }
                float nx = __builtin_fmaf(rot[v].x, w[v].x, -(rot[v].y * w[v].y));
                float ny = __builtin_fmaf(rot[v].x, w[v].y,  (rot[v].y * w[v].x));
                rot[v] = make_float2(nx, ny);
            }
        }
        // j+3 (odd) -> F3, H3
        {
            float2 yv[8];
#pragma unroll
            for (int u = 0; u < 8; ++u) yv[u] = ys[j + 3][c * 2 + (u & 1) + (u >> 1) * 16];
#pragma unroll
            for (int v = 0; v < 2; ++v) {
                const float cx = rot[v].x, sx = rot[v].y;
#pragma unroll
                for (int u = 0; u < 8; ++u) {
                    float a = F3[v][u], g = H3[v][u];
                    a = __builtin_fmaf(cx, yv[u].x, a);
                    a = __builtin_fmaf(-sx, yv[u].y, a);
                    g = __builtin_fmaf(sx, yv[u].x, g);
                    g = __builtin_fmaf(cx, yv[u].y, g);
                    F3[v][u] = a; H3[v][u] = g;
                }
                float nx = __builtin_fmaf(rot[v].x, w[v].x, -(rot[v].y * w[v].y));
                float ny = __builtin_fmaf(rot[v].x, w[v].y,  (rot[v].y * w[v].x));
                rot[v] = make_float2(nx, ny);
            }
        }
    }

    // stores: 4 rows per (v): l0+v, +1024, +2048, +3072
#pragma unroll
    for (int v = 0; v < 2; ++v) {
        float* o0 = out + ((size_t)(b * 4096 + l0 + v)) * 512 + (size_t)hft * 64;
        float* o1 = o0 + (size_t)1024 * 512;
        float* o2 = o0 + (size_t)2048 * 512;
        float* o3 = o0 + (size_t)3072 * 512;
#pragma unroll
        for (int k = 0; k < 4; ++k) {
            float2 s0, s1, s2, s3;
#pragma unroll
            for (int d = 0; d < 2; ++d) {
                const int u = 2 * k + d;
                const float p = F0[v][u] + F2[v][u];
                const float m = F0[v][u] - F2[v][u];
                const float q = F1[v][u] + F3[v][u];
                const float hh = H3[v][u] - H1[v][u];
                ((float*)&s0)[d] = p + q;
                ((float*)&s2)[d] = p - q;
                ((float*)&s1)[d] = m + hh;
                ((float*)&s3)[d] = m - hh;
            }
            *(float2*)(o0 + k * 16 + c * 2) = s0;
            *(float2*)(o1 + k * 16 + c * 2) = s1;
            *(float2*)(o2 + k * 16 + c * 2) = s2;
            *(float2*)(o3 + k * 16 + c * 2) = s3;
        }
    }
}

// ---------------- launch ----------------
extern "C" void kernel_launch(void* const* d_in, const int* in_sizes, int n_in,
                              void* d_out, int out_size, void* d_ws, size_t ws_size,
                              hipStream_t stream) {
    const float* q  = (const float*)d_in[0];
    const float* wr = (const float*)d_in[3];
    const float* wi = (const float*)d_in[4];

    char* ws = (char*)d_ws;
    float2*             trig  = (float2*)(ws + 0);                  // 32 KB
    unsigned long long* score = (unsigned long long*)(ws + 32768);  // 16 KB
    int*                idx   = (int*)(ws + 49152);                 // 256 B
    float2*             Y     = (float2*)(ws + 65536);              // 4 MB

    // d_out triples as: transposed-q scratch T -> spectrum Xout (in-place) -> final output.
    float2* Xs = (float2*)d_out;

    hipMemsetAsync(score, 0, 2048 * sizeof(unsigned long long), stream);
    k_tables<<<16, 256, 0, stream>>>(trig);
    k_xpose<<<2048, 256, 0, stream>>>(q, Xs);          // (b:16, h:8, c4:16)
    k_fft<<<1024, 256, 0, stream>>>(trig, Xs, score);  // in-place T -> spectra
    k_topk<<<8, 256, 0, stream>>>(score, idx);         // 2048 candidates, 1/thread
    k_proj<<<512, 256, 0, stream>>>(Xs, wr, wi, idx, Y);
    k_synth<<<2048, 256, 0, stream>>>(Y, trig, (float*)d_out);  // (b:16, hft:8, lt:16)
}